// Round 7
// baseline (896.223 us; speedup 1.0000x reference)
//
#include <hip/hip_runtime.h>

constexpr int N_NODES = 100000;
constexpr int N_EDGES = 1600000;
constexpr int T_OUT = 112;

constexpr int SCAN_CHUNK = 1024;
constexpr int SCAN_BLOCKS = (N_NODES + SCAN_CHUNK - 1) / SCAN_CHUNK;  // 98
constexpr int AGG_BLOCKS = 2048;  // persistent-ish grid-stride (4 resident/CU)

typedef _Float16 h2v __attribute__((ext_vector_type(2)));
typedef _Float16 half8 __attribute__((ext_vector_type(8)));
typedef float f32x4 __attribute__((ext_vector_type(4)));
typedef int i4v __attribute__((ext_vector_type(4)));
typedef float f4v __attribute__((ext_vector_type(4)));

__device__ __forceinline__ float dot2h(h2v a, h2v b, float c) {
#if __has_builtin(__builtin_amdgcn_fdot2)
    return __builtin_amdgcn_fdot2(a, b, c, false);
#else
    return fmaf((float)a.x, (float)b.x, fmaf((float)a.y, (float)b.y, c));
#endif
}
__device__ __forceinline__ int pk2(float a, float b) {
    auto v = __builtin_amdgcn_cvt_pkrtz(a, b);  // __fp16 ext_vector(2)
    return __builtin_bit_cast(int, v);
}
__device__ __forceinline__ h2v b2h(int x) { return __builtin_bit_cast(h2v, x); }
__device__ __forceinline__ unsigned short f2h(float f) {
    return __builtin_bit_cast(unsigned short, (_Float16)f);
}
__device__ __forceinline__ float h2f(unsigned short u) {
    return (float)__builtin_bit_cast(_Float16, u);
}

// ---------------------------------------------------------------------------
// Wc_h2[lg][4][64] (half2-packed over input channel pairs), bcomb[lg][64].
__global__ void wcomb_kernel(const float* __restrict__ W_ee,
                             const float* __restrict__ b_ee,
                             const float* __restrict__ We,
                             const float* __restrict__ be,
                             int* __restrict__ Wc_h2,
                             float* __restrict__ bcomb) {
    int lg = blockIdx.x;
    int d = threadIdx.x;
    const float* We_ = We + (size_t)lg * 128 * 64;
    float acc[9];
#pragma unroll
    for (int k = 0; k < 9; ++k) acc[k] = 0.f;
    for (int c = 0; c < 128; ++c) {
        float wv = We_[c * 64 + d];
#pragma unroll
        for (int k = 0; k < 8; ++k) acc[k] += W_ee[k * 128 + c] * wv;
        acc[8] += b_ee[c] * wv;
    }
#pragma unroll
    for (int j = 0; j < 4; ++j)
        Wc_h2[lg * 256 + j * 64 + d] = pk2(acc[2 * j], acc[2 * j + 1]);
    bcomb[lg * 64 + d] = acc[8] + be[lg * 64 + d];
}

// ---------------------------------------------------------------------------
// Pack Wp[128][112] fp32 -> fp16 MFMA B-fragments.
__global__ void wp_pack_kernel(const float* __restrict__ Wp, int* __restrict__ wpfrag) {
    int tm = blockIdx.x;  // 0..27
    int tile = tm >> 2, m = tm & 3;
    int lane = threadIdx.x;
    int g = lane >> 4, r = lane & 15;
    int t = tile * 16 + r;
    int o[4];
#pragma unroll
    for (int p = 0; p < 4; ++p) {
        int j0 = 2 * p, j1 = 2 * p + 1;
        int k0 = m * 32 + (j0 >> 2) * 16 + g * 4 + (j0 & 3);
        int k1 = m * 32 + (j1 >> 2) * 16 + g * 4 + (j1 & 3);
        o[p] = pk2(Wp[k0 * 112 + t], Wp[k1 * 112 + t]);
    }
    int4 o4; o4.x = o[0]; o4.y = o[1]; o4.z = o[2]; o4.w = o[3];
    *(int4*)(wpfrag + ((size_t)tm * 64 + lane) * 4) = o4;
}

// ---------------------------------------------------------------------------
__global__ __launch_bounds__(256) void encoder_kernel(
    const float* __restrict__ x, const int* __restrict__ node_index,
    const float* __restrict__ node_features,
    const float* __restrict__ W_oh, const float* __restrict__ b_oh,
    const float* __restrict__ W_ne, const float* __restrict__ b_ne,
    float* __restrict__ A, float* __restrict__ B) {
    int tid = threadIdx.x;
    int w = tid >> 6, d = tid & 63;
    int n = blockIdx.x * 4 + w;

    float xf[8];
    const float* xr = x + (size_t)n * 8;
#pragma unroll
    for (int j = 0; j < 8; ++j) xf[j] = xr[j];

    float nf[16];
    int ni = node_index[n];
    const float* nfr = node_features + (size_t)ni * 8;
#pragma unroll
    for (int k = 0; k < 8; ++k) nf[k] = nfr[k];
#pragma unroll
    for (int k = 0; k < 8; ++k) {
        float acc = b_oh[k];
#pragma unroll
        for (int j = 0; j < 8; ++j) acc += xf[j] * W_oh[j * 8 + k];
        nf[8 + k] = acc;
    }
    float hA = b_ne[d], hB = b_ne[64 + d];
#pragma unroll
    for (int k = 0; k < 16; ++k) {
        hA += nf[k] * W_ne[k * 128 + d];
        hB += nf[k] * W_ne[k * 128 + 64 + d];
    }
    A[(size_t)n * 64 + d] = hA;
    B[(size_t)n * 64 + d] = hB;
}

// ---------------------------------------------------------------------------
// CSR build
__global__ void hist_kernel(const int* __restrict__ edge_index, int* __restrict__ deg) {
    int e = blockIdx.x * 256 + threadIdx.x;
    if (e < N_EDGES) atomicAdd(&deg[edge_index[N_EDGES + e]], 1);
}

__global__ __launch_bounds__(256) void block_sum_kernel(const int* __restrict__ deg,
                                                        int* __restrict__ blocksum) {
    __shared__ int s_w[4];
    int t = threadIdx.x;
    int base = blockIdx.x * SCAN_CHUNK + t * 4;
    int s = 0;
    if (base + 3 < N_NODES) {
        int4 v = *(const int4*)(deg + base);
        s = v.x + v.y + v.z + v.w;
    } else {
        for (int j = 0; j < 4; ++j)
            if (base + j < N_NODES) s += deg[base + j];
    }
#pragma unroll
    for (int o = 32; o >= 1; o >>= 1) s += __shfl_xor(s, o, 64);
    if ((t & 63) == 0) s_w[t >> 6] = s;
    __syncthreads();
    if (t == 0) blocksum[blockIdx.x] = s_w[0] + s_w[1] + s_w[2] + s_w[3];
}

__global__ __launch_bounds__(64) void scan_sums_kernel(const int* __restrict__ blocksum,
                                                       int* __restrict__ blockoff,
                                                       int* __restrict__ rowptr) {
    int t = threadIdx.x;
    int i0 = 2 * t, i1 = 2 * t + 1;
    int v0 = (i0 < SCAN_BLOCKS) ? blocksum[i0] : 0;
    int v1 = (i1 < SCAN_BLOCKS) ? blocksum[i1] : 0;
    int s = v0 + v1;
    int incl = s;
#pragma unroll
    for (int o = 1; o < 64; o <<= 1) {
        int u = __shfl_up(incl, o, 64);
        if (t >= o) incl += u;
    }
    int excl = incl - s;
    if (i0 < SCAN_BLOCKS) blockoff[i0] = excl;
    if (i1 < SCAN_BLOCKS) blockoff[i1] = excl + v0;
    if (t == 63) rowptr[N_NODES] = incl;
}

__global__ __launch_bounds__(256) void emit_kernel(const int* __restrict__ deg,
                                                   const int* __restrict__ blockoff,
                                                   int* __restrict__ rowptr,
                                                   int* __restrict__ pos) {
    __shared__ int s_w[4];
    int t = threadIdx.x;
    int w = t >> 6, lane = t & 63;
    int base = blockIdx.x * SCAN_CHUNK + t * 4;

    int d0 = 0, d1 = 0, d2 = 0, d3 = 0;
    if (base + 3 < N_NODES) {
        int4 v = *(const int4*)(deg + base);
        d0 = v.x; d1 = v.y; d2 = v.z; d3 = v.w;
    } else {
        if (base + 0 < N_NODES) d0 = deg[base + 0];
        if (base + 1 < N_NODES) d1 = deg[base + 1];
        if (base + 2 < N_NODES) d2 = deg[base + 2];
        if (base + 3 < N_NODES) d3 = deg[base + 3];
    }
    int s = d0 + d1 + d2 + d3;
    int incl = s;
#pragma unroll
    for (int o = 1; o < 64; o <<= 1) {
        int u = __shfl_up(incl, o, 64);
        if (lane >= o) incl += u;
    }
    if (lane == 63) s_w[w] = incl;
    __syncthreads();
    int woff = 0;
    for (int j = 0; j < 4; ++j) woff += (j < w) ? s_w[j] : 0;

    int p = blockoff[blockIdx.x] + woff + incl - s;
    int4 r;
    r.x = p;
    r.y = p + d0;
    r.z = p + d0 + d1;
    r.w = p + d0 + d1 + d2;
    if (base + 3 < N_NODES) {
        *(int4*)(rowptr + base) = r;
        *(int4*)(pos + base) = r;
    } else {
        if (base + 0 < N_NODES) { rowptr[base + 0] = r.x; pos[base + 0] = r.x; }
        if (base + 1 < N_NODES) { rowptr[base + 1] = r.y; pos[base + 1] = r.y; }
        if (base + 2 < N_NODES) { rowptr[base + 2] = r.z; pos[base + 2] = r.z; }
        if (base + 3 < N_NODES) { rowptr[base + 3] = r.w; pos[base + 3] = r.w; }
    }
}

// Scatter edges into dst-sorted order; edge_attr converted to packed half8.
// Nontemporal hints: scattered writes shouldn't allocate in cache.
__global__ void scatter_kernel(const int* __restrict__ edge_index,
                               const float* __restrict__ edge_attr,
                               int* __restrict__ pos,
                               int* __restrict__ src_perm,
                               int* __restrict__ ea_h) {
    int e = blockIdx.x * 256 + threadIdx.x;
    if (e >= N_EDGES) return;
    int dn = edge_index[N_EDGES + e];
    int idx = atomicAdd(&pos[dn], 1);
    f4v a = __builtin_nontemporal_load((const f4v*)(edge_attr + (size_t)e * 8));
    f4v b = __builtin_nontemporal_load((const f4v*)(edge_attr + (size_t)e * 8 + 4));
    i4v o;
    o.x = pk2(a.x, a.y);
    o.y = pk2(a.z, a.w);
    o.z = pk2(b.x, b.y);
    o.w = pk2(b.z, b.w);
    __builtin_nontemporal_store(o, (i4v*)(ea_h + (size_t)idx * 4));
    __builtin_nontemporal_store(edge_index[e], src_perm + idx);
}

// ---------------------------------------------------------------------------
// hl (fp16) = relu(LayerNorm(Y) * g + b)  — only needed for the FIRST block;
// subsequent blocks get hl from the fused agg epilogue.
__global__ __launch_bounds__(256) void ln_relu_kernel(const float* __restrict__ Y,
                                                      const float* __restrict__ g,
                                                      const float* __restrict__ b,
                                                      unsigned short* __restrict__ hl16) {
    int tid = threadIdx.x;
    int w = tid >> 6, d = tid & 63;
    int n = blockIdx.x * 4 + w;
    float y = Y[(size_t)n * 64 + d];
    float s = y, sq = y * y;
#pragma unroll
    for (int offd = 32; offd >= 1; offd >>= 1) {
        s += __shfl_xor(s, offd, 64);
        sq += __shfl_xor(sq, offd, 64);
    }
    float mean = s * (1.f / 64.f);
    float var = sq * (1.f / 64.f) - mean * mean;
    float rs = rsqrtf(var + 1e-5f);
    float h = (y - mean) * rs * g[d] + b[d];
    hl16[(size_t)n * 64 + d] = f2h(fmaxf(h, 0.f));
}

// ---------------------------------------------------------------------------
// Softmax aggregation (CSR gather) + epilogue (hl+agg)@Wm + residual into Y
// + (fused) next block's LayerNorm+ReLU -> hl_out.
// Grid-stride over nodes (1 wave/node per iteration) to absorb degree skew.
template <bool PRODUCE_HL>
__global__ __launch_bounds__(512) void agg_epi_kernel(
    const unsigned short* __restrict__ hl_in, unsigned short* __restrict__ hl_out,
    float* __restrict__ Y,
    const int* __restrict__ rowptr, const int* __restrict__ src_perm,
    const int* __restrict__ ea_h,
    const int* __restrict__ Wc_h2, const float* __restrict__ bcomb,
    const float* __restrict__ Wm, const float* __restrict__ bm,
    const float* __restrict__ gnext, const float* __restrict__ bnext) {
    __shared__ float s_wm[4096];
    __shared__ int s_wc2[256];
    __shared__ float s_v[512];
    int tid = threadIdx.x;
    if (tid < 256) s_wc2[tid] = Wc_h2[tid];
    for (int i = tid; i < 4096; i += 512) s_wm[i] = Wm[i];
    __syncthreads();

    int w = tid >> 6, d = tid & 63;

    h2v wcA = b2h(s_wc2[0 * 64 + d]);
    h2v wcB = b2h(s_wc2[1 * 64 + d]);
    h2v wcC = b2h(s_wc2[2 * 64 + d]);
    h2v wcD = b2h(s_wc2[3 * 64 + d]);
    float bc = bcomb[d];
    float bmd = bm[d];
    float gn = 0.f, bn = 0.f;
    if constexpr (PRODUCE_HL) { gn = gnext[d]; bn = bnext[d]; }

    const int4* ea4 = (const int4*)ea_h;
    const int nwaves = gridDim.x * 8;

#define RFL(X) __builtin_amdgcn_readfirstlane(X)
#define EDGE(U, E)                                                    \
    {                                                                 \
        float eW = bc;                                                \
        eW = dot2h(b2h(E.x), wcA, eW);                                \
        eW = dot2h(b2h(E.y), wcB, eW);                                \
        eW = dot2h(b2h(E.z), wcC, eW);                                \
        eW = dot2h(b2h(E.w), wcD, eW);                                \
        float m = fmaxf(h2f(U) + eW, 0.f) + 1e-7f;                    \
        float ex = __expf(m);                                         \
        den += ex;                                                    \
        num += ex * m;                                                \
    }

    for (int n0 = blockIdx.x * 8 + w; n0 < N_NODES; n0 += nwaves) {
        int n = RFL(n0);
        float num = 0.f, den = 0.f;
        int start = rowptr[n], end = rowptr[n + 1];

        int i = start;
        for (; i + 8 <= end; i += 8) {
            int s0 = RFL(src_perm[i + 0]), s1 = RFL(src_perm[i + 1]);
            int s2 = RFL(src_perm[i + 2]), s3 = RFL(src_perm[i + 3]);
            int s4 = RFL(src_perm[i + 4]), s5 = RFL(src_perm[i + 5]);
            int s6 = RFL(src_perm[i + 6]), s7 = RFL(src_perm[i + 7]);
            unsigned short u0 = hl_in[(size_t)s0 * 64 + d];
            unsigned short u1 = hl_in[(size_t)s1 * 64 + d];
            unsigned short u2 = hl_in[(size_t)s2 * 64 + d];
            unsigned short u3 = hl_in[(size_t)s3 * 64 + d];
            unsigned short u4 = hl_in[(size_t)s4 * 64 + d];
            unsigned short u5 = hl_in[(size_t)s5 * 64 + d];
            unsigned short u6 = hl_in[(size_t)s6 * 64 + d];
            unsigned short u7 = hl_in[(size_t)s7 * 64 + d];
            int4 e0 = ea4[i + 0], e1 = ea4[i + 1], e2 = ea4[i + 2], e3 = ea4[i + 3];
            EDGE(u0, e0) EDGE(u1, e1) EDGE(u2, e2) EDGE(u3, e3)
            int4 e4 = ea4[i + 4], e5 = ea4[i + 5], e6 = ea4[i + 6], e7 = ea4[i + 7];
            EDGE(u4, e4) EDGE(u5, e5) EDGE(u6, e6) EDGE(u7, e7)
        }
        for (; i + 4 <= end; i += 4) {
            int s0 = RFL(src_perm[i + 0]), s1 = RFL(src_perm[i + 1]);
            int s2 = RFL(src_perm[i + 2]), s3 = RFL(src_perm[i + 3]);
            unsigned short u0 = hl_in[(size_t)s0 * 64 + d];
            unsigned short u1 = hl_in[(size_t)s1 * 64 + d];
            unsigned short u2 = hl_in[(size_t)s2 * 64 + d];
            unsigned short u3 = hl_in[(size_t)s3 * 64 + d];
            int4 e0 = ea4[i + 0], e1 = ea4[i + 1], e2 = ea4[i + 2], e3 = ea4[i + 3];
            EDGE(u0, e0) EDGE(u1, e1) EDGE(u2, e2) EDGE(u3, e3)
        }
        for (; i < end; ++i) {
            int s0 = RFL(src_perm[i]);
            unsigned short u0 = hl_in[(size_t)s0 * 64 + d];
            int4 e0 = ea4[i];
            EDGE(u0, e0)
        }

        float agg = num / (den + 1e-16f);
        float v = h2f(hl_in[(size_t)n * 64 + d]) + agg;
        s_v[w * 64 + d] = v;  // wave-local: no block barrier needed
        float acc = bmd;
        for (int k = 0; k < 64; ++k) acc += s_v[w * 64 + k] * s_wm[k * 64 + d];

        float ynew = Y[(size_t)n * 64 + d] + acc;
        Y[(size_t)n * 64 + d] = ynew;

        if constexpr (PRODUCE_HL) {
            // next block's LN+ReLU, fused (wave holds all 64 channels)
            float s = ynew, sq = ynew * ynew;
#pragma unroll
            for (int o = 32; o >= 1; o >>= 1) {
                s += __shfl_xor(s, o, 64);
                sq += __shfl_xor(sq, o, 64);
            }
            float mean = s * (1.f / 64.f);
            float var = sq * (1.f / 64.f) - mean * mean;
            float rs = rsqrtf(var + 1e-5f);
            float h = (ynew - mean) * rs * gn + bn;
            hl_out[(size_t)n * 64 + d] = f2h(fmaxf(h, 0.f));
        }
    }
#undef EDGE
#undef RFL
}

// ---------------------------------------------------------------------------
// Final: LN(128) -> relu -> MFMA GEMM @Wp + bp.
__global__ __launch_bounds__(256) void final_kernel(
    const float* __restrict__ A, const float* __restrict__ B,
    const float* __restrict__ lg, const float* __restrict__ lb,
    const int* __restrict__ wpfrag, const float* __restrict__ bp,
    float* __restrict__ out) {
    int tid = threadIdx.x;
    int w = tid >> 6, lane = tid & 63;
    int g = lane >> 4, r = lane & 15;
    int nodebase = blockIdx.x * 64 + w * 16;
    if (nodebase >= N_NODES) return;
    int n = nodebase + r;

    float4 v[8];
    const float4* A4 = (const float4*)(A + (size_t)n * 64);
    const float4* B4 = (const float4*)(B + (size_t)n * 64);
#pragma unroll
    for (int kb = 0; kb < 4; ++kb) v[kb] = A4[kb * 4 + g];
#pragma unroll
    for (int kb = 0; kb < 4; ++kb) v[4 + kb] = B4[kb * 4 + g];

    float s = 0.f, sq = 0.f;
#pragma unroll
    for (int kb = 0; kb < 8; ++kb) {
        s += v[kb].x + v[kb].y + v[kb].z + v[kb].w;
        sq += v[kb].x * v[kb].x + v[kb].y * v[kb].y
            + v[kb].z * v[kb].z + v[kb].w * v[kb].w;
    }
    s += __shfl_xor(s, 16, 64);  sq += __shfl_xor(sq, 16, 64);
    s += __shfl_xor(s, 32, 64);  sq += __shfl_xor(sq, 32, 64);
    float mean = s * (1.f / 128.f);
    float var = sq * (1.f / 128.f) - mean * mean;
    float rs = rsqrtf(var + 1e-5f);

    const float4* lg4 = (const float4*)lg;
    const float4* lb4 = (const float4*)lb;
    half8 afr[4];
#pragma unroll
    for (int kb = 0; kb < 8; ++kb) {
        float4 gv = lg4[kb * 4 + g];
        float4 bv = lb4[kb * 4 + g];
        int m = kb >> 1, e0 = (kb & 1) * 4;
        afr[m][e0 + 0] = (_Float16)fmaxf((v[kb].x - mean) * rs * gv.x + bv.x, 0.f);
        afr[m][e0 + 1] = (_Float16)fmaxf((v[kb].y - mean) * rs * gv.y + bv.y, 0.f);
        afr[m][e0 + 2] = (_Float16)fmaxf((v[kb].z - mean) * rs * gv.z + bv.z, 0.f);
        afr[m][e0 + 3] = (_Float16)fmaxf((v[kb].w - mean) * rs * gv.w + bv.w, 0.f);
    }

    const int4* wf4 = (const int4*)wpfrag;
#pragma unroll
    for (int tile = 0; tile < 7; ++tile) {
        float bias = bp[tile * 16 + r];
        f32x4 acc = {bias, bias, bias, bias};
#pragma unroll
        for (int m = 0; m < 4; ++m) {
            int4 bw = wf4[(tile * 4 + m) * 64 + lane];
            half8 bf = __builtin_bit_cast(half8, bw);
            acc = __builtin_amdgcn_mfma_f32_16x16x32_f16(afr[m], bf, acc, 0, 0, 0);
        }
#pragma unroll
        for (int q = 0; q < 4; ++q) {
            out[(size_t)(nodebase + g * 4 + q) * T_OUT + tile * 16 + r] = acc[q];
        }
    }
}

// ---------------------------------------------------------------------------
extern "C" void kernel_launch(void* const* d_in, const int* in_sizes, int n_in,
                              void* d_out, int out_size, void* d_ws, size_t ws_size,
                              hipStream_t stream) {
    const float* x            = (const float*)d_in[0];
    const int* node_index     = (const int*)d_in[1];
    const int* edge_index     = (const int*)d_in[2];
    const float* edge_attr    = (const float*)d_in[3];
    const float* node_features= (const float*)d_in[4];
    const float* W_oh         = (const float*)d_in[5];
    const float* b_oh         = (const float*)d_in[6];
    const float* W_ne         = (const float*)d_in[7];
    const float* b_ne         = (const float*)d_in[8];
    const float* W_ee         = (const float*)d_in[9];
    const float* b_ee         = (const float*)d_in[10];
    const float* ln_g         = (const float*)d_in[11];
    const float* ln_b         = (const float*)d_in[12];
    const float* We           = (const float*)d_in[13];
    const float* be           = (const float*)d_in[14];
    const float* Wm           = (const float*)d_in[15];
    const float* bm           = (const float*)d_in[16];
    const float* last_g       = (const float*)d_in[17];
    const float* last_b       = (const float*)d_in[18];
    const float* Wp           = (const float*)d_in[19];
    const float* bp           = (const float*)d_in[20];
    float* out = (float*)d_out;

    char* ws = (char*)d_ws;
    size_t off = 0;
    auto alloc = [&](size_t bytes) -> void* {
        void* p = ws + off;
        off = (off + bytes + 255) & ~(size_t)255;
        return p;
    };
    float* A          = (float*)alloc((size_t)N_NODES * 64 * 4);
    float* B          = (float*)alloc((size_t)N_NODES * 64 * 4);
    unsigned short* hlA = (unsigned short*)alloc((size_t)N_NODES * 64 * 2);
    unsigned short* hlB = (unsigned short*)alloc((size_t)N_NODES * 64 * 2);
    int* deg          = (int*)alloc((size_t)N_NODES * 4);
    int* rowptr       = (int*)alloc((size_t)(N_NODES + 1) * 4);
    int* pos          = (int*)alloc((size_t)N_NODES * 4);
    int* src_perm     = (int*)alloc((size_t)N_EDGES * 4);
    int* ea_h         = (int*)alloc((size_t)N_EDGES * 4 * 4);  // half8 per edge
    int* Wc_h2        = (int*)alloc(4 * 256 * 4);
    float* bcomb      = (float*)alloc(4 * 64 * 4);
    int* blocksum     = (int*)alloc((size_t)SCAN_BLOCKS * 4);
    int* blockoff     = (int*)alloc((size_t)SCAN_BLOCKS * 4);
    int* wpfrag       = (int*)alloc((size_t)28 * 64 * 16);     // 28 KB
    (void)ws_size; (void)in_sizes; (void)n_in; (void)out_size;

    const int NB_NODE = N_NODES / 4;            // 25000
    const int NB_EDGE = (N_EDGES + 255) / 256;  // 6250

    (void)hipMemsetAsync(deg, 0, (size_t)N_NODES * 4, stream);
    wcomb_kernel<<<4, 64, 0, stream>>>(W_ee, b_ee, We, be, Wc_h2, bcomb);
    wp_pack_kernel<<<28, 64, 0, stream>>>(Wp, wpfrag);
    encoder_kernel<<<NB_NODE, 256, 0, stream>>>(x, node_index, node_features,
                                                W_oh, b_oh, W_ne, b_ne, A, B);
    hist_kernel<<<NB_EDGE, 256, 0, stream>>>(edge_index, deg);
    block_sum_kernel<<<SCAN_BLOCKS, 256, 0, stream>>>(deg, blocksum);
    scan_sums_kernel<<<1, 64, 0, stream>>>(blocksum, blockoff, rowptr);
    emit_kernel<<<SCAN_BLOCKS, 256, 0, stream>>>(deg, blockoff, rowptr, pos);
    scatter_kernel<<<NB_EDGE, 256, 0, stream>>>(edge_index, edge_attr, pos,
                                                src_perm, ea_h);

    // block 0 input LN (y_in = B half)
    ln_relu_kernel<<<NB_NODE, 256, 0, stream>>>(B, ln_g, ln_b, hlA);

    // gen-block 0: in hlA, out A; produce hl for block 1 (params ln[1])
    agg_epi_kernel<true><<<AGG_BLOCKS, 512, 0, stream>>>(
        hlA, hlB, A, rowptr, src_perm, ea_h,
        Wc_h2 + 0 * 256, bcomb + 0 * 64, Wm + (size_t)0 * 4096, bm + 0 * 64,
        ln_g + 1 * 64, ln_b + 1 * 64);
    // gen-block 1: in hlB, out B; produce hl for block 2 (params ln[2])
    agg_epi_kernel<true><<<AGG_BLOCKS, 512, 0, stream>>>(
        hlB, hlA, B, rowptr, src_perm, ea_h,
        Wc_h2 + 1 * 256, bcomb + 1 * 64, Wm + (size_t)1 * 4096, bm + 1 * 64,
        ln_g + 2 * 64, ln_b + 2 * 64);
    // gen-block 2: in hlA, out A; produce hl for block 3 (params ln[3])
    agg_epi_kernel<true><<<AGG_BLOCKS, 512, 0, stream>>>(
        hlA, hlB, A, rowptr, src_perm, ea_h,
        Wc_h2 + 2 * 256, bcomb + 2 * 64, Wm + (size_t)2 * 4096, bm + 2 * 64,
        ln_g + 3 * 64, ln_b + 3 * 64);
    // gen-block 3: in hlB, out B; no hl production
    agg_epi_kernel<false><<<AGG_BLOCKS, 512, 0, stream>>>(
        hlB, hlA, B, rowptr, src_perm, ea_h,
        Wc_h2 + 3 * 256, bcomb + 3 * 64, Wm + (size_t)3 * 4096, bm + 3 * 64,
        ln_g, ln_b);

    final_kernel<<<(N_NODES + 63) / 64, 256, 0, stream>>>(
        A, B, last_g, last_b, wpfrag, bp, out);
}

// Round 8
// 623.625 us; speedup vs baseline: 1.4371x; 1.4371x over previous
//
#include <hip/hip_runtime.h>

constexpr int N_NODES = 100000;
constexpr int N_EDGES = 1600000;
constexpr int T_OUT = 112;

constexpr int SCAN_CHUNK = 1024;
constexpr int SCAN_BLOCKS = (N_NODES + SCAN_CHUNK - 1) / SCAN_CHUNK;  // 98

typedef _Float16 h2v __attribute__((ext_vector_type(2)));
typedef _Float16 half4 __attribute__((ext_vector_type(4)));
typedef _Float16 half8 __attribute__((ext_vector_type(8)));
typedef float f32x4 __attribute__((ext_vector_type(4)));
typedef int i4v __attribute__((ext_vector_type(4)));
typedef float f4v __attribute__((ext_vector_type(4)));

__device__ __forceinline__ float dot2h(h2v a, h2v b, float c) {
#if __has_builtin(__builtin_amdgcn_fdot2)
    return __builtin_amdgcn_fdot2(a, b, c, false);
#else
    return fmaf((float)a.x, (float)b.x, fmaf((float)a.y, (float)b.y, c));
#endif
}
__device__ __forceinline__ int pk2(float a, float b) {
    auto v = __builtin_amdgcn_cvt_pkrtz(a, b);
    return __builtin_bit_cast(int, v);
}
__device__ __forceinline__ h2v b2h(int x) { return __builtin_bit_cast(h2v, x); }
__device__ __forceinline__ unsigned short f2h(float f) {
    return __builtin_bit_cast(unsigned short, (_Float16)f);
}
__device__ __forceinline__ float h2f(unsigned short u) {
    return (float)__builtin_bit_cast(_Float16, u);
}

// ---------------------------------------------------------------------------
// Wc_h2[lg][4][64] (half2-packed input-channel pairs), bcomb[lg][64].
__global__ void wcomb_kernel(const float* __restrict__ W_ee,
                             const float* __restrict__ b_ee,
                             const float* __restrict__ We,
                             const float* __restrict__ be,
                             int* __restrict__ Wc_h2,
                             float* __restrict__ bcomb) {
    int lg = blockIdx.x;
    int d = threadIdx.x;
    const float* We_ = We + (size_t)lg * 128 * 64;
    float acc[9];
#pragma unroll
    for (int k = 0; k < 9; ++k) acc[k] = 0.f;
    for (int c = 0; c < 128; ++c) {
        float wv = We_[c * 64 + d];
#pragma unroll
        for (int k = 0; k < 8; ++k) acc[k] += W_ee[k * 128 + c] * wv;
        acc[8] += b_ee[c] * wv;
    }
#pragma unroll
    for (int j = 0; j < 4; ++j)
        Wc_h2[lg * 256 + j * 64 + d] = pk2(acc[2 * j], acc[2 * j + 1]);
    bcomb[lg * 64 + d] = acc[8] + be[lg * 64 + d];
}

// ---------------------------------------------------------------------------
// Pack Wp[128][112] fp32 -> fp16 MFMA B-fragments (7 tiles x 4 K-halves).
__global__ void wp_pack_kernel(const float* __restrict__ Wp, int* __restrict__ wpfrag) {
    int tm = blockIdx.x;  // 0..27
    int tile = tm >> 2, m = tm & 3;
    int lane = threadIdx.x;
    int g = lane >> 4, r = lane & 15;
    int t = tile * 16 + r;
    int o[4];
#pragma unroll
    for (int p = 0; p < 4; ++p) {
        int j0 = 2 * p, j1 = 2 * p + 1;
        int k0 = m * 32 + (j0 >> 2) * 16 + g * 4 + (j0 & 3);
        int k1 = m * 32 + (j1 >> 2) * 16 + g * 4 + (j1 & 3);
        o[p] = pk2(Wp[k0 * 112 + t], Wp[k1 * 112 + t]);
    }
    int4 o4; o4.x = o[0]; o4.y = o[1]; o4.z = o[2]; o4.w = o[3];
    *(int4*)(wpfrag + ((size_t)tm * 64 + lane) * 4) = o4;
}

// Pack Wm[lg][64][64] fp32 -> fp16 MFMA B-fragments (4 tiles x 2 K-halves per lg).
__global__ void wm_pack_kernel(const float* __restrict__ Wm, int* __restrict__ wmfrag) {
    int b = blockIdx.x;  // lg*8 + tile*2 + m, 32 blocks
    int lg = b >> 3, tm = b & 7;
    int tile = tm >> 1, m = tm & 1;
    int lane = threadIdx.x;
    int g = lane >> 4, r = lane & 15;
    const float* W = Wm + (size_t)lg * 4096;
    int col = tile * 16 + r;
    int o[4];
#pragma unroll
    for (int p = 0; p < 4; ++p) {
        int j0 = 2 * p, j1 = 2 * p + 1;
        int k0 = m * 32 + (j0 >> 2) * 16 + g * 4 + (j0 & 3);
        int k1 = m * 32 + (j1 >> 2) * 16 + g * 4 + (j1 & 3);
        o[p] = pk2(W[k0 * 64 + col], W[k1 * 64 + col]);
    }
    int4 o4; o4.x = o[0]; o4.y = o[1]; o4.z = o[2]; o4.w = o[3];
    *(int4*)(wmfrag + ((size_t)b * 64 + lane) * 4) = o4;
}

// ---------------------------------------------------------------------------
__global__ __launch_bounds__(256) void encoder_kernel(
    const float* __restrict__ x, const int* __restrict__ node_index,
    const float* __restrict__ node_features,
    const float* __restrict__ W_oh, const float* __restrict__ b_oh,
    const float* __restrict__ W_ne, const float* __restrict__ b_ne,
    float* __restrict__ A, float* __restrict__ B) {
    int tid = threadIdx.x;
    int w = tid >> 6, d = tid & 63;
    int n = blockIdx.x * 4 + w;

    float xf[8];
    const float* xr = x + (size_t)n * 8;
#pragma unroll
    for (int j = 0; j < 8; ++j) xf[j] = xr[j];

    float nf[16];
    int ni = node_index[n];
    const float* nfr = node_features + (size_t)ni * 8;
#pragma unroll
    for (int k = 0; k < 8; ++k) nf[k] = nfr[k];
#pragma unroll
    for (int k = 0; k < 8; ++k) {
        float acc = b_oh[k];
#pragma unroll
        for (int j = 0; j < 8; ++j) acc += xf[j] * W_oh[j * 8 + k];
        nf[8 + k] = acc;
    }
    float hA = b_ne[d], hB = b_ne[64 + d];
#pragma unroll
    for (int k = 0; k < 16; ++k) {
        hA += nf[k] * W_ne[k * 128 + d];
        hB += nf[k] * W_ne[k * 128 + 64 + d];
    }
    A[(size_t)n * 64 + d] = hA;
    B[(size_t)n * 64 + d] = hB;
}

// ---------------------------------------------------------------------------
// CSR build
__global__ void hist_kernel(const int* __restrict__ edge_index, int* __restrict__ deg) {
    int e = blockIdx.x * 256 + threadIdx.x;
    if (e < N_EDGES) atomicAdd(&deg[edge_index[N_EDGES + e]], 1);
}

__global__ __launch_bounds__(256) void block_sum_kernel(const int* __restrict__ deg,
                                                        int* __restrict__ blocksum) {
    __shared__ int s_w[4];
    int t = threadIdx.x;
    int base = blockIdx.x * SCAN_CHUNK + t * 4;
    int s = 0;
    if (base + 3 < N_NODES) {
        int4 v = *(const int4*)(deg + base);
        s = v.x + v.y + v.z + v.w;
    } else {
        for (int j = 0; j < 4; ++j)
            if (base + j < N_NODES) s += deg[base + j];
    }
#pragma unroll
    for (int o = 32; o >= 1; o >>= 1) s += __shfl_xor(s, o, 64);
    if ((t & 63) == 0) s_w[t >> 6] = s;
    __syncthreads();
    if (t == 0) blocksum[blockIdx.x] = s_w[0] + s_w[1] + s_w[2] + s_w[3];
}

__global__ __launch_bounds__(64) void scan_sums_kernel(const int* __restrict__ blocksum,
                                                       int* __restrict__ blockoff,
                                                       int* __restrict__ rowptr) {
    int t = threadIdx.x;
    int i0 = 2 * t, i1 = 2 * t + 1;
    int v0 = (i0 < SCAN_BLOCKS) ? blocksum[i0] : 0;
    int v1 = (i1 < SCAN_BLOCKS) ? blocksum[i1] : 0;
    int s = v0 + v1;
    int incl = s;
#pragma unroll
    for (int o = 1; o < 64; o <<= 1) {
        int u = __shfl_up(incl, o, 64);
        if (t >= o) incl += u;
    }
    int excl = incl - s;
    if (i0 < SCAN_BLOCKS) blockoff[i0] = excl;
    if (i1 < SCAN_BLOCKS) blockoff[i1] = excl + v0;
    if (t == 63) rowptr[N_NODES] = incl;
}

__global__ __launch_bounds__(256) void emit_kernel(const int* __restrict__ deg,
                                                   const int* __restrict__ blockoff,
                                                   int* __restrict__ rowptr,
                                                   int* __restrict__ pos) {
    __shared__ int s_w[4];
    int t = threadIdx.x;
    int w = t >> 6, lane = t & 63;
    int base = blockIdx.x * SCAN_CHUNK + t * 4;

    int d0 = 0, d1 = 0, d2 = 0, d3 = 0;
    if (base + 3 < N_NODES) {
        int4 v = *(const int4*)(deg + base);
        d0 = v.x; d1 = v.y; d2 = v.z; d3 = v.w;
    } else {
        if (base + 0 < N_NODES) d0 = deg[base + 0];
        if (base + 1 < N_NODES) d1 = deg[base + 1];
        if (base + 2 < N_NODES) d2 = deg[base + 2];
        if (base + 3 < N_NODES) d3 = deg[base + 3];
    }
    int s = d0 + d1 + d2 + d3;
    int incl = s;
#pragma unroll
    for (int o = 1; o < 64; o <<= 1) {
        int u = __shfl_up(incl, o, 64);
        if (lane >= o) incl += u;
    }
    if (lane == 63) s_w[w] = incl;
    __syncthreads();
    int woff = 0;
    for (int j = 0; j < 4; ++j) woff += (j < w) ? s_w[j] : 0;

    int p = blockoff[blockIdx.x] + woff + incl - s;
    int4 r;
    r.x = p;
    r.y = p + d0;
    r.z = p + d0 + d1;
    r.w = p + d0 + d1 + d2;
    if (base + 3 < N_NODES) {
        *(int4*)(rowptr + base) = r;
        *(int4*)(pos + base) = r;
    } else {
        if (base + 0 < N_NODES) { rowptr[base + 0] = r.x; pos[base + 0] = r.x; }
        if (base + 1 < N_NODES) { rowptr[base + 1] = r.y; pos[base + 1] = r.y; }
        if (base + 2 < N_NODES) { rowptr[base + 2] = r.z; pos[base + 2] = r.z; }
        if (base + 3 < N_NODES) { rowptr[base + 3] = r.w; pos[base + 3] = r.w; }
    }
}

// Scatter edges into dst-sorted order; edge_attr converted to packed half8.
__global__ void scatter_kernel(const int* __restrict__ edge_index,
                               const float* __restrict__ edge_attr,
                               int* __restrict__ pos,
                               int* __restrict__ src_perm,
                               int* __restrict__ ea_h) {
    int e = blockIdx.x * 256 + threadIdx.x;
    if (e >= N_EDGES) return;
    int dn = edge_index[N_EDGES + e];
    int idx = atomicAdd(&pos[dn], 1);
    f4v a = __builtin_nontemporal_load((const f4v*)(edge_attr + (size_t)e * 8));
    f4v b = __builtin_nontemporal_load((const f4v*)(edge_attr + (size_t)e * 8 + 4));
    i4v o;
    o.x = pk2(a.x, a.y);
    o.y = pk2(a.z, a.w);
    o.z = pk2(b.x, b.y);
    o.w = pk2(b.z, b.w);
    __builtin_nontemporal_store(o, (i4v*)(ea_h + (size_t)idx * 4));
    __builtin_nontemporal_store(edge_index[e], src_perm + idx);
}

// ---------------------------------------------------------------------------
// hl (fp16) = relu(LayerNorm(Y) * g + b) — first gen-block input only.
__global__ __launch_bounds__(256) void ln_relu_kernel(const float* __restrict__ Y,
                                                      const float* __restrict__ g,
                                                      const float* __restrict__ b,
                                                      unsigned short* __restrict__ hl16) {
    int tid = threadIdx.x;
    int w = tid >> 6, d = tid & 63;
    int n = blockIdx.x * 4 + w;
    float y = Y[(size_t)n * 64 + d];
    float s = y, sq = y * y;
#pragma unroll
    for (int offd = 32; offd >= 1; offd >>= 1) {
        s += __shfl_xor(s, offd, 64);
        sq += __shfl_xor(sq, offd, 64);
    }
    float mean = s * (1.f / 64.f);
    float var = sq * (1.f / 64.f) - mean * mean;
    float rs = rsqrtf(var + 1e-5f);
    float h = (y - mean) * rs * g[d] + b[d];
    hl16[(size_t)n * 64 + d] = f2h(fmaxf(h, 0.f));
}

// ---------------------------------------------------------------------------
// Gather + scatter-softmax aggregation ONLY (no epilogue, no LDS, no barrier).
// 1 wave per node, 256-thr blocks. Writes v = hl_self + agg as fp16.
__global__ __launch_bounds__(256) void agg_kernel(
    const unsigned short* __restrict__ hl_in, unsigned short* __restrict__ v16,
    const int* __restrict__ rowptr, const int* __restrict__ src_perm,
    const int* __restrict__ ea_h,
    const int* __restrict__ Wc_h2, const float* __restrict__ bcomb) {
    int tid = threadIdx.x;
    int w = tid >> 6, d = tid & 63;
    int n = __builtin_amdgcn_readfirstlane(blockIdx.x * 4 + w);

    h2v wcA = b2h(Wc_h2[0 * 64 + d]);
    h2v wcB = b2h(Wc_h2[1 * 64 + d]);
    h2v wcC = b2h(Wc_h2[2 * 64 + d]);
    h2v wcD = b2h(Wc_h2[3 * 64 + d]);
    float bc = bcomb[d];

    float num = 0.f, den = 0.f;
    int start = rowptr[n], end = rowptr[n + 1];
    const int4* ea4 = (const int4*)ea_h;

#define RFL(X) __builtin_amdgcn_readfirstlane(X)
#define EDGE(U, E)                                                    \
    {                                                                 \
        float eW = bc;                                                \
        eW = dot2h(b2h(E.x), wcA, eW);                                \
        eW = dot2h(b2h(E.y), wcB, eW);                                \
        eW = dot2h(b2h(E.z), wcC, eW);                                \
        eW = dot2h(b2h(E.w), wcD, eW);                                \
        float m = fmaxf(h2f(U) + eW, 0.f) + 1e-7f;                    \
        float ex = __expf(m);                                         \
        den += ex;                                                    \
        num += ex * m;                                                \
    }

    int i = start;
    for (; i + 8 <= end; i += 8) {
        int s0 = RFL(src_perm[i + 0]), s1 = RFL(src_perm[i + 1]);
        int s2 = RFL(src_perm[i + 2]), s3 = RFL(src_perm[i + 3]);
        int s4 = RFL(src_perm[i + 4]), s5 = RFL(src_perm[i + 5]);
        int s6 = RFL(src_perm[i + 6]), s7 = RFL(src_perm[i + 7]);
        unsigned short u0 = hl_in[(size_t)s0 * 64 + d];
        unsigned short u1 = hl_in[(size_t)s1 * 64 + d];
        unsigned short u2 = hl_in[(size_t)s2 * 64 + d];
        unsigned short u3 = hl_in[(size_t)s3 * 64 + d];
        unsigned short u4 = hl_in[(size_t)s4 * 64 + d];
        unsigned short u5 = hl_in[(size_t)s5 * 64 + d];
        unsigned short u6 = hl_in[(size_t)s6 * 64 + d];
        unsigned short u7 = hl_in[(size_t)s7 * 64 + d];
        int4 e0 = ea4[i + 0], e1 = ea4[i + 1], e2 = ea4[i + 2], e3 = ea4[i + 3];
        EDGE(u0, e0) EDGE(u1, e1) EDGE(u2, e2) EDGE(u3, e3)
        int4 e4 = ea4[i + 4], e5 = ea4[i + 5], e6 = ea4[i + 6], e7 = ea4[i + 7];
        EDGE(u4, e4) EDGE(u5, e5) EDGE(u6, e6) EDGE(u7, e7)
    }
    for (; i + 4 <= end; i += 4) {
        int s0 = RFL(src_perm[i + 0]), s1 = RFL(src_perm[i + 1]);
        int s2 = RFL(src_perm[i + 2]), s3 = RFL(src_perm[i + 3]);
        unsigned short u0 = hl_in[(size_t)s0 * 64 + d];
        unsigned short u1 = hl_in[(size_t)s1 * 64 + d];
        unsigned short u2 = hl_in[(size_t)s2 * 64 + d];
        unsigned short u3 = hl_in[(size_t)s3 * 64 + d];
        int4 e0 = ea4[i + 0], e1 = ea4[i + 1], e2 = ea4[i + 2], e3 = ea4[i + 3];
        EDGE(u0, e0) EDGE(u1, e1) EDGE(u2, e2) EDGE(u3, e3)
    }
    for (; i < end; ++i) {
        int s0 = RFL(src_perm[i]);
        unsigned short u0 = hl_in[(size_t)s0 * 64 + d];
        int4 e0 = ea4[i];
        EDGE(u0, e0)
    }
#undef EDGE
#undef RFL

    float agg = num / (den + 1e-16f);
    float v = h2f(hl_in[(size_t)n * 64 + d]) + agg;
    v16[(size_t)n * 64 + d] = f2h(v);
}

// ---------------------------------------------------------------------------
// Epilogue: Y += v @ Wm + bm (MFMA), then fused next-LN+ReLU -> hl_out.
// 256 thr = 4 waves x 16 nodes; fragment layouts identical to final_kernel.
template <bool PRODUCE_HL>
__global__ __launch_bounds__(256) void epi_kernel(
    const unsigned short* __restrict__ v16, float* __restrict__ Y,
    const int* __restrict__ wmfrag, const float* __restrict__ bm,
    const float* __restrict__ gnext, const float* __restrict__ bnext,
    unsigned short* __restrict__ hl_out) {
    int tid = threadIdx.x;
    int w = tid >> 6, lane = tid & 63;
    int g = lane >> 4, r = lane & 15;
    int nodebase = blockIdx.x * 64 + w * 16;
    if (nodebase >= N_NODES) return;

    // A-fragments: node = nodebase + r, k-elem e: m*32 + (e>>2)*16 + g*4 + (e&3)
    const unsigned short* vp = v16 + (size_t)(nodebase + r) * 64;
    half8 af[2];
#pragma unroll
    for (int m = 0; m < 2; ++m) {
        int k0 = m * 32 + g * 4;
        half4 lo = *(const half4*)(vp + k0);
        half4 hi = *(const half4*)(vp + k0 + 16);
        af[m][0] = lo[0]; af[m][1] = lo[1]; af[m][2] = lo[2]; af[m][3] = lo[3];
        af[m][4] = hi[0]; af[m][5] = hi[1]; af[m][6] = hi[2]; af[m][7] = hi[3];
    }

    const int4* wf4 = (const int4*)wmfrag;
    f32x4 acc[4];
#pragma unroll
    for (int tile = 0; tile < 4; ++tile) {
        float bmv = bm[tile * 16 + r];
        acc[tile] = {bmv, bmv, bmv, bmv};
#pragma unroll
        for (int m = 0; m < 2; ++m) {
            int4 bw = wf4[(tile * 2 + m) * 64 + lane];
            half8 bf = __builtin_bit_cast(half8, bw);
            acc[tile] = __builtin_amdgcn_mfma_f32_16x16x32_f16(af[m], bf, acc[tile], 0, 0, 0);
        }
    }

    // residual: ynew = Y + acc; C layout: node = nodebase+g*4+q, ch = tile*16+r
    float yn[4][4];  // [tile][q]
#pragma unroll
    for (int tile = 0; tile < 4; ++tile) {
#pragma unroll
        for (int q = 0; q < 4; ++q) {
            size_t idx = (size_t)(nodebase + g * 4 + q) * 64 + tile * 16 + r;
            float y = Y[idx] + acc[tile][q];
            yn[tile][q] = y;
            Y[idx] = y;
        }
    }

    if constexpr (PRODUCE_HL) {
        float gnv[4], bnv[4];
#pragma unroll
        for (int tile = 0; tile < 4; ++tile) {
            gnv[tile] = gnext[tile * 16 + r];
            bnv[tile] = bnext[tile * 16 + r];
        }
#pragma unroll
        for (int q = 0; q < 4; ++q) {
            float s = yn[0][q] + yn[1][q] + yn[2][q] + yn[3][q];
            float sq = yn[0][q] * yn[0][q] + yn[1][q] * yn[1][q]
                     + yn[2][q] * yn[2][q] + yn[3][q] * yn[3][q];
            s += __shfl_xor(s, 1, 64);  sq += __shfl_xor(sq, 1, 64);
            s += __shfl_xor(s, 2, 64);  sq += __shfl_xor(sq, 2, 64);
            s += __shfl_xor(s, 4, 64);  sq += __shfl_xor(sq, 4, 64);
            s += __shfl_xor(s, 8, 64);  sq += __shfl_xor(sq, 8, 64);
            float mean = s * (1.f / 64.f);
            float var = sq * (1.f / 64.f) - mean * mean;
            float rs = rsqrtf(var + 1e-5f);
#pragma unroll
            for (int tile = 0; tile < 4; ++tile) {
                float h = (yn[tile][q] - mean) * rs * gnv[tile] + bnv[tile];
                hl_out[(size_t)(nodebase + g * 4 + q) * 64 + tile * 16 + r] =
                    f2h(fmaxf(h, 0.f));
            }
        }
    }
}

// ---------------------------------------------------------------------------
// Final: LN(128) -> relu -> MFMA GEMM @Wp + bp.
__global__ __launch_bounds__(256) void final_kernel(
    const float* __restrict__ A, const float* __restrict__ B,
    const float* __restrict__ lg, const float* __restrict__ lb,
    const int* __restrict__ wpfrag, const float* __restrict__ bp,
    float* __restrict__ out) {
    int tid = threadIdx.x;
    int w = tid >> 6, lane = tid & 63;
    int g = lane >> 4, r = lane & 15;
    int nodebase = blockIdx.x * 64 + w * 16;
    if (nodebase >= N_NODES) return;
    int n = nodebase + r;

    float4 v[8];
    const float4* A4 = (const float4*)(A + (size_t)n * 64);
    const float4* B4 = (const float4*)(B + (size_t)n * 64);
#pragma unroll
    for (int kb = 0; kb < 4; ++kb) v[kb] = A4[kb * 4 + g];
#pragma unroll
    for (int kb = 0; kb < 4; ++kb) v[4 + kb] = B4[kb * 4 + g];

    float s = 0.f, sq = 0.f;
#pragma unroll
    for (int kb = 0; kb < 8; ++kb) {
        s += v[kb].x + v[kb].y + v[kb].z + v[kb].w;
        sq += v[kb].x * v[kb].x + v[kb].y * v[kb].y
            + v[kb].z * v[kb].z + v[kb].w * v[kb].w;
    }
    s += __shfl_xor(s, 16, 64);  sq += __shfl_xor(sq, 16, 64);
    s += __shfl_xor(s, 32, 64);  sq += __shfl_xor(sq, 32, 64);
    float mean = s * (1.f / 128.f);
    float var = sq * (1.f / 128.f) - mean * mean;
    float rs = rsqrtf(var + 1e-5f);

    const float4* lg4 = (const float4*)lg;
    const float4* lb4 = (const float4*)lb;
    half8 afr[4];
#pragma unroll
    for (int kb = 0; kb < 8; ++kb) {
        float4 gv = lg4[kb * 4 + g];
        float4 bv = lb4[kb * 4 + g];
        int m = kb >> 1, e0 = (kb & 1) * 4;
        afr[m][e0 + 0] = (_Float16)fmaxf((v[kb].x - mean) * rs * gv.x + bv.x, 0.f);
        afr[m][e0 + 1] = (_Float16)fmaxf((v[kb].y - mean) * rs * gv.y + bv.y, 0.f);
        afr[m][e0 + 2] = (_Float16)fmaxf((v[kb].z - mean) * rs * gv.z + bv.z, 0.f);
        afr[m][e0 + 3] = (_Float16)fmaxf((v[kb].w - mean) * rs * gv.w + bv.w, 0.f);
    }

    const int4* wf4 = (const int4*)wpfrag;
#pragma unroll
    for (int tile = 0; tile < 7; ++tile) {
        float bias = bp[tile * 16 + r];
        f32x4 acc = {bias, bias, bias, bias};
#pragma unroll
        for (int m = 0; m < 4; ++m) {
            int4 bw = wf4[(tile * 4 + m) * 64 + lane];
            half8 bf = __builtin_bit_cast(half8, bw);
            acc = __builtin_amdgcn_mfma_f32_16x16x32_f16(afr[m], bf, acc, 0, 0, 0);
        }
#pragma unroll
        for (int q = 0; q < 4; ++q) {
            out[(size_t)(nodebase + g * 4 + q) * T_OUT + tile * 16 + r] = acc[q];
        }
    }
}

// ---------------------------------------------------------------------------
extern "C" void kernel_launch(void* const* d_in, const int* in_sizes, int n_in,
                              void* d_out, int out_size, void* d_ws, size_t ws_size,
                              hipStream_t stream) {
    const float* x            = (const float*)d_in[0];
    const int* node_index     = (const int*)d_in[1];
    const int* edge_index     = (const int*)d_in[2];
    const float* edge_attr    = (const float*)d_in[3];
    const float* node_features= (const float*)d_in[4];
    const float* W_oh         = (const float*)d_in[5];
    const float* b_oh         = (const float*)d_in[6];
    const float* W_ne         = (const float*)d_in[7];
    const float* b_ne         = (const float*)d_in[8];
    const float* W_ee         = (const float*)d_in[9];
    const float* b_ee         = (const float*)d_in[10];
    const float* ln_g         = (const float*)d_in[11];
    const float* ln_b         = (const float*)d_in[12];
    const float* We           = (const float*)d_in[13];
    const float* be           = (const float*)d_in[14];
    const float* Wm           = (const float*)d_in[15];
    const float* bm           = (const float*)d_in[16];
    const float* last_g       = (const float*)d_in[17];
    const float* last_b       = (const float*)d_in[18];
    const float* Wp           = (const float*)d_in[19];
    const float* bp           = (const float*)d_in[20];
    float* out = (float*)d_out;

    char* ws = (char*)d_ws;
    size_t off = 0;
    auto alloc = [&](size_t bytes) -> void* {
        void* p = ws + off;
        off = (off + bytes + 255) & ~(size_t)255;
        return p;
    };
    float* A          = (float*)alloc((size_t)N_NODES * 64 * 4);
    float* B          = (float*)alloc((size_t)N_NODES * 64 * 4);
    unsigned short* hl = (unsigned short*)alloc((size_t)N_NODES * 64 * 2);
    unsigned short* v16 = (unsigned short*)alloc((size_t)N_NODES * 64 * 2);
    int* deg          = (int*)alloc((size_t)N_NODES * 4);
    int* rowptr       = (int*)alloc((size_t)(N_NODES + 1) * 4);
    int* pos          = (int*)alloc((size_t)N_NODES * 4);
    int* src_perm     = (int*)alloc((size_t)N_EDGES * 4);
    int* ea_h         = (int*)alloc((size_t)N_EDGES * 4 * 4);  // half8 per edge
    int* Wc_h2        = (int*)alloc(4 * 256 * 4);
    float* bcomb      = (float*)alloc(4 * 64 * 4);
    int* blocksum     = (int*)alloc((size_t)SCAN_BLOCKS * 4);
    int* blockoff     = (int*)alloc((size_t)SCAN_BLOCKS * 4);
    int* wpfrag       = (int*)alloc((size_t)28 * 64 * 16);     // 28 KB
    int* wmfrag       = (int*)alloc((size_t)32 * 64 * 16);     // 32 KB
    (void)ws_size; (void)in_sizes; (void)n_in; (void)out_size;

    const int NB_NODE = N_NODES / 4;            // 25000
    const int NB_EDGE = (N_EDGES + 255) / 256;  // 6250
    const int NB_EPI  = (N_NODES + 63) / 64;    // 1563

    (void)hipMemsetAsync(deg, 0, (size_t)N_NODES * 4, stream);
    wcomb_kernel<<<4, 64, 0, stream>>>(W_ee, b_ee, We, be, Wc_h2, bcomb);
    wp_pack_kernel<<<28, 64, 0, stream>>>(Wp, wpfrag);
    wm_pack_kernel<<<32, 64, 0, stream>>>(Wm, wmfrag);
    encoder_kernel<<<NB_NODE, 256, 0, stream>>>(x, node_index, node_features,
                                                W_oh, b_oh, W_ne, b_ne, A, B);
    hist_kernel<<<NB_EDGE, 256, 0, stream>>>(edge_index, deg);
    block_sum_kernel<<<SCAN_BLOCKS, 256, 0, stream>>>(deg, blocksum);
    scan_sums_kernel<<<1, 64, 0, stream>>>(blocksum, blockoff, rowptr);
    emit_kernel<<<SCAN_BLOCKS, 256, 0, stream>>>(deg, blockoff, rowptr, pos);
    scatter_kernel<<<NB_EDGE, 256, 0, stream>>>(edge_index, edge_attr, pos,
                                                src_perm, ea_h);

    // first gen-block input LN (y_in = B half, params ln[0])
    ln_relu_kernel<<<NB_NODE, 256, 0, stream>>>(B, ln_g, ln_b, hl);

    // gen-block 0: Y = A; produce hl for block 1 (ln[1])
    agg_kernel<<<NB_NODE, 256, 0, stream>>>(hl, v16, rowptr, src_perm, ea_h,
                                            Wc_h2 + 0 * 256, bcomb + 0 * 64);
    epi_kernel<true><<<NB_EPI, 256, 0, stream>>>(
        v16, A, wmfrag + 0 * 8 * 256, bm + 0 * 64,
        ln_g + 1 * 64, ln_b + 1 * 64, hl);
    // gen-block 1: Y = B; produce hl for block 2 (ln[2])
    agg_kernel<<<NB_NODE, 256, 0, stream>>>(hl, v16, rowptr, src_perm, ea_h,
                                            Wc_h2 + 1 * 256, bcomb + 1 * 64);
    epi_kernel<true><<<NB_EPI, 256, 0, stream>>>(
        v16, B, wmfrag + 1 * 8 * 256, bm + 1 * 64,
        ln_g + 2 * 64, ln_b + 2 * 64, hl);
    // gen-block 2: Y = A; produce hl for block 3 (ln[3])
    agg_kernel<<<NB_NODE, 256, 0, stream>>>(hl, v16, rowptr, src_perm, ea_h,
                                            Wc_h2 + 2 * 256, bcomb + 2 * 64);
    epi_kernel<true><<<NB_EPI, 256, 0, stream>>>(
        v16, A, wmfrag + 2 * 8 * 256, bm + 2 * 64,
        ln_g + 3 * 64, ln_b + 3 * 64, hl);
    // gen-block 3: Y = B; no hl production
    agg_kernel<<<NB_NODE, 256, 0, stream>>>(hl, v16, rowptr, src_perm, ea_h,
                                            Wc_h2 + 3 * 256, bcomb + 3 * 64);
    epi_kernel<false><<<NB_EPI, 256, 0, stream>>>(
        v16, B, wmfrag + 3 * 8 * 256, bm + 3 * 64,
        nullptr, nullptr, nullptr);

    final_kernel<<<NB_EPI, 256, 0, stream>>>(A, B, last_g, last_b, wpfrag, bp, out);
}

// Round 9
// 611.571 us; speedup vs baseline: 1.4654x; 1.0197x over previous
//
#include <hip/hip_runtime.h>

constexpr int N_NODES = 100000;
constexpr int N_EDGES = 1600000;
constexpr int T_OUT = 112;

constexpr int SCAN_CHUNK = 1024;
constexpr int SCAN_BLOCKS = (N_NODES + SCAN_CHUNK - 1) / SCAN_CHUNK;  // 98

typedef _Float16 h2v __attribute__((ext_vector_type(2)));
typedef _Float16 half4 __attribute__((ext_vector_type(4)));
typedef _Float16 half8 __attribute__((ext_vector_type(8)));
typedef float f32x4 __attribute__((ext_vector_type(4)));
typedef int i4v __attribute__((ext_vector_type(4)));
typedef float f4v __attribute__((ext_vector_type(4)));

__device__ __forceinline__ float dot2h(h2v a, h2v b, float c) {
#if __has_builtin(__builtin_amdgcn_fdot2)
    return __builtin_amdgcn_fdot2(a, b, c, false);
#else
    return fmaf((float)a.x, (float)b.x, fmaf((float)a.y, (float)b.y, c));
#endif
}
__device__ __forceinline__ int pk2(float a, float b) {
    auto v = __builtin_amdgcn_cvt_pkrtz(a, b);
    return __builtin_bit_cast(int, v);
}
__device__ __forceinline__ h2v b2h(int x) { return __builtin_bit_cast(h2v, x); }
__device__ __forceinline__ unsigned short f2h(float f) {
    return __builtin_bit_cast(unsigned short, (_Float16)f);
}
__device__ __forceinline__ float h2f(unsigned short u) {
    return (float)__builtin_bit_cast(_Float16, u);
}

// ---------------------------------------------------------------------------
// Wc_h2[lg][4][64] (half2-packed input-channel pairs), bcomb[lg][64].
__global__ void wcomb_kernel(const float* __restrict__ W_ee,
                             const float* __restrict__ b_ee,
                             const float* __restrict__ We,
                             const float* __restrict__ be,
                             int* __restrict__ Wc_h2,
                             float* __restrict__ bcomb) {
    int lg = blockIdx.x;
    int d = threadIdx.x;
    const float* We_ = We + (size_t)lg * 128 * 64;
    float acc[9];
#pragma unroll
    for (int k = 0; k < 9; ++k) acc[k] = 0.f;
    for (int c = 0; c < 128; ++c) {
        float wv = We_[c * 64 + d];
#pragma unroll
        for (int k = 0; k < 8; ++k) acc[k] += W_ee[k * 128 + c] * wv;
        acc[8] += b_ee[c] * wv;
    }
#pragma unroll
    for (int j = 0; j < 4; ++j)
        Wc_h2[lg * 256 + j * 64 + d] = pk2(acc[2 * j], acc[2 * j + 1]);
    bcomb[lg * 64 + d] = acc[8] + be[lg * 64 + d];
}

// ---------------------------------------------------------------------------
// Pack Wp[128][112] fp32 -> fp16 MFMA B-fragments (7 tiles x 4 K-halves).
__global__ void wp_pack_kernel(const float* __restrict__ Wp, int* __restrict__ wpfrag) {
    int tm = blockIdx.x;  // 0..27
    int tile = tm >> 2, m = tm & 3;
    int lane = threadIdx.x;
    int g = lane >> 4, r = lane & 15;
    int t = tile * 16 + r;
    int o[4];
#pragma unroll
    for (int p = 0; p < 4; ++p) {
        int j0 = 2 * p, j1 = 2 * p + 1;
        int k0 = m * 32 + (j0 >> 2) * 16 + g * 4 + (j0 & 3);
        int k1 = m * 32 + (j1 >> 2) * 16 + g * 4 + (j1 & 3);
        o[p] = pk2(Wp[k0 * 112 + t], Wp[k1 * 112 + t]);
    }
    int4 o4; o4.x = o[0]; o4.y = o[1]; o4.z = o[2]; o4.w = o[3];
    *(int4*)(wpfrag + ((size_t)tm * 64 + lane) * 4) = o4;
}

// Pack Wm[lg][64][64] fp32 -> fp16 MFMA B-fragments (4 tiles x 2 K-halves per lg).
__global__ void wm_pack_kernel(const float* __restrict__ Wm, int* __restrict__ wmfrag) {
    int b = blockIdx.x;  // lg*8 + tile*2 + m, 32 blocks
    int lg = b >> 3, tm = b & 7;
    int tile = tm >> 1, m = tm & 1;
    int lane = threadIdx.x;
    int g = lane >> 4, r = lane & 15;
    const float* W = Wm + (size_t)lg * 4096;
    int col = tile * 16 + r;
    int o[4];
#pragma unroll
    for (int p = 0; p < 4; ++p) {
        int j0 = 2 * p, j1 = 2 * p + 1;
        int k0 = m * 32 + (j0 >> 2) * 16 + g * 4 + (j0 & 3);
        int k1 = m * 32 + (j1 >> 2) * 16 + g * 4 + (j1 & 3);
        o[p] = pk2(W[k0 * 64 + col], W[k1 * 64 + col]);
    }
    int4 o4; o4.x = o[0]; o4.y = o[1]; o4.z = o[2]; o4.w = o[3];
    *(int4*)(wmfrag + ((size_t)b * 64 + lane) * 4) = o4;
}

// ---------------------------------------------------------------------------
__global__ __launch_bounds__(256) void encoder_kernel(
    const float* __restrict__ x, const int* __restrict__ node_index,
    const float* __restrict__ node_features,
    const float* __restrict__ W_oh, const float* __restrict__ b_oh,
    const float* __restrict__ W_ne, const float* __restrict__ b_ne,
    float* __restrict__ A, float* __restrict__ B) {
    int tid = threadIdx.x;
    int w = tid >> 6, d = tid & 63;
    int n = blockIdx.x * 4 + w;

    float xf[8];
    const float* xr = x + (size_t)n * 8;
#pragma unroll
    for (int j = 0; j < 8; ++j) xf[j] = xr[j];

    float nf[16];
    int ni = node_index[n];
    const float* nfr = node_features + (size_t)ni * 8;
#pragma unroll
    for (int k = 0; k < 8; ++k) nf[k] = nfr[k];
#pragma unroll
    for (int k = 0; k < 8; ++k) {
        float acc = b_oh[k];
#pragma unroll
        for (int j = 0; j < 8; ++j) acc += xf[j] * W_oh[j * 8 + k];
        nf[8 + k] = acc;
    }
    float hA = b_ne[d], hB = b_ne[64 + d];
#pragma unroll
    for (int k = 0; k < 16; ++k) {
        hA += nf[k] * W_ne[k * 128 + d];
        hB += nf[k] * W_ne[k * 128 + 64 + d];
    }
    A[(size_t)n * 64 + d] = hA;
    B[(size_t)n * 64 + d] = hB;
}

// ---------------------------------------------------------------------------
// CSR build. hist also records each edge's within-node rank (atomic return),
// making the scatter pass atomic-free: slot = rowptr[dst] + rank.
__global__ void hist_kernel(const int* __restrict__ edge_index,
                            int* __restrict__ deg, int* __restrict__ rank) {
    int e = blockIdx.x * 256 + threadIdx.x;
    if (e < N_EDGES) rank[e] = atomicAdd(&deg[edge_index[N_EDGES + e]], 1);
}

__global__ __launch_bounds__(256) void block_sum_kernel(const int* __restrict__ deg,
                                                        int* __restrict__ blocksum) {
    __shared__ int s_w[4];
    int t = threadIdx.x;
    int base = blockIdx.x * SCAN_CHUNK + t * 4;
    int s = 0;
    if (base + 3 < N_NODES) {
        int4 v = *(const int4*)(deg + base);
        s = v.x + v.y + v.z + v.w;
    } else {
        for (int j = 0; j < 4; ++j)
            if (base + j < N_NODES) s += deg[base + j];
    }
#pragma unroll
    for (int o = 32; o >= 1; o >>= 1) s += __shfl_xor(s, o, 64);
    if ((t & 63) == 0) s_w[t >> 6] = s;
    __syncthreads();
    if (t == 0) blocksum[blockIdx.x] = s_w[0] + s_w[1] + s_w[2] + s_w[3];
}

__global__ __launch_bounds__(64) void scan_sums_kernel(const int* __restrict__ blocksum,
                                                       int* __restrict__ blockoff,
                                                       int* __restrict__ rowptr) {
    int t = threadIdx.x;
    int i0 = 2 * t, i1 = 2 * t + 1;
    int v0 = (i0 < SCAN_BLOCKS) ? blocksum[i0] : 0;
    int v1 = (i1 < SCAN_BLOCKS) ? blocksum[i1] : 0;
    int s = v0 + v1;
    int incl = s;
#pragma unroll
    for (int o = 1; o < 64; o <<= 1) {
        int u = __shfl_up(incl, o, 64);
        if (t >= o) incl += u;
    }
    int excl = incl - s;
    if (i0 < SCAN_BLOCKS) blockoff[i0] = excl;
    if (i1 < SCAN_BLOCKS) blockoff[i1] = excl + v0;
    if (t == 63) rowptr[N_NODES] = incl;
}

__global__ __launch_bounds__(256) void emit_kernel(const int* __restrict__ deg,
                                                   const int* __restrict__ blockoff,
                                                   int* __restrict__ rowptr) {
    __shared__ int s_w[4];
    int t = threadIdx.x;
    int w = t >> 6, lane = t & 63;
    int base = blockIdx.x * SCAN_CHUNK + t * 4;

    int d0 = 0, d1 = 0, d2 = 0, d3 = 0;
    if (base + 3 < N_NODES) {
        int4 v = *(const int4*)(deg + base);
        d0 = v.x; d1 = v.y; d2 = v.z; d3 = v.w;
    } else {
        if (base + 0 < N_NODES) d0 = deg[base + 0];
        if (base + 1 < N_NODES) d1 = deg[base + 1];
        if (base + 2 < N_NODES) d2 = deg[base + 2];
        if (base + 3 < N_NODES) d3 = deg[base + 3];
    }
    int s = d0 + d1 + d2 + d3;
    int incl = s;
#pragma unroll
    for (int o = 1; o < 64; o <<= 1) {
        int u = __shfl_up(incl, o, 64);
        if (lane >= o) incl += u;
    }
    if (lane == 63) s_w[w] = incl;
    __syncthreads();
    int woff = 0;
    for (int j = 0; j < 4; ++j) woff += (j < w) ? s_w[j] : 0;

    int p = blockoff[blockIdx.x] + woff + incl - s;
    int4 r;
    r.x = p;
    r.y = p + d0;
    r.z = p + d0 + d1;
    r.w = p + d0 + d1 + d2;
    if (base + 3 < N_NODES) {
        *(int4*)(rowptr + base) = r;
    } else {
        if (base + 0 < N_NODES) rowptr[base + 0] = r.x;
        if (base + 1 < N_NODES) rowptr[base + 1] = r.y;
        if (base + 2 < N_NODES) rowptr[base + 2] = r.z;
        if (base + 3 < N_NODES) rowptr[base + 3] = r.w;
    }
}

// Atomic-free scatter: slot = rowptr[dst] + rank (precomputed in hist).
// Pure fire-and-forget stores; edge_attr converted to packed half8.
__global__ void scatter_kernel(const int* __restrict__ edge_index,
                               const float* __restrict__ edge_attr,
                               const int* __restrict__ rowptr,
                               const int* __restrict__ rank,
                               int* __restrict__ src_perm,
                               int* __restrict__ ea_h) {
    int e = blockIdx.x * 256 + threadIdx.x;
    if (e >= N_EDGES) return;
    int dn = edge_index[N_EDGES + e];
    int idx = rowptr[dn] + rank[e];
    f4v a = __builtin_nontemporal_load((const f4v*)(edge_attr + (size_t)e * 8));
    f4v b = __builtin_nontemporal_load((const f4v*)(edge_attr + (size_t)e * 8 + 4));
    i4v o;
    o.x = pk2(a.x, a.y);
    o.y = pk2(a.z, a.w);
    o.z = pk2(b.x, b.y);
    o.w = pk2(b.z, b.w);
    __builtin_nontemporal_store(o, (i4v*)(ea_h + (size_t)idx * 4));
    __builtin_nontemporal_store(edge_index[e], src_perm + idx);
}

// ---------------------------------------------------------------------------
// hl (fp16) = relu(LayerNorm(Y) * g + b) — first gen-block input only.
__global__ __launch_bounds__(256) void ln_relu_kernel(const float* __restrict__ Y,
                                                      const float* __restrict__ g,
                                                      const float* __restrict__ b,
                                                      unsigned short* __restrict__ hl16) {
    int tid = threadIdx.x;
    int w = tid >> 6, d = tid & 63;
    int n = blockIdx.x * 4 + w;
    float y = Y[(size_t)n * 64 + d];
    float s = y, sq = y * y;
#pragma unroll
    for (int offd = 32; offd >= 1; offd >>= 1) {
        s += __shfl_xor(s, offd, 64);
        sq += __shfl_xor(sq, offd, 64);
    }
    float mean = s * (1.f / 64.f);
    float var = sq * (1.f / 64.f) - mean * mean;
    float rs = rsqrtf(var + 1e-5f);
    float h = (y - mean) * rs * g[d] + b[d];
    hl16[(size_t)n * 64 + d] = f2h(fmaxf(h, 0.f));
}

// ---------------------------------------------------------------------------
// Gather + scatter-softmax aggregation ONLY (no epilogue, no LDS, no barrier).
// 1 wave per node, 256-thr blocks. Writes v = hl_self + agg as fp16.
__global__ __launch_bounds__(256) void agg_kernel(
    const unsigned short* __restrict__ hl_in, unsigned short* __restrict__ v16,
    const int* __restrict__ rowptr, const int* __restrict__ src_perm,
    const int* __restrict__ ea_h,
    const int* __restrict__ Wc_h2, const float* __restrict__ bcomb) {
    int tid = threadIdx.x;
    int w = tid >> 6, d = tid & 63;
    int n = __builtin_amdgcn_readfirstlane(blockIdx.x * 4 + w);

    h2v wcA = b2h(Wc_h2[0 * 64 + d]);
    h2v wcB = b2h(Wc_h2[1 * 64 + d]);
    h2v wcC = b2h(Wc_h2[2 * 64 + d]);
    h2v wcD = b2h(Wc_h2[3 * 64 + d]);
    float bc = bcomb[d];

    float num = 0.f, den = 0.f;
    int start = rowptr[n], end = rowptr[n + 1];
    const int4* ea4 = (const int4*)ea_h;

#define RFL(X) __builtin_amdgcn_readfirstlane(X)
#define EDGE(U, E)                                                    \
    {                                                                 \
        float eW = bc;                                                \
        eW = dot2h(b2h(E.x), wcA, eW);                                \
        eW = dot2h(b2h(E.y), wcB, eW);                                \
        eW = dot2h(b2h(E.z), wcC, eW);                                \
        eW = dot2h(b2h(E.w), wcD, eW);                                \
        float m = fmaxf(h2f(U) + eW, 0.f) + 1e-7f;                    \
        float ex = __expf(m);                                         \
        den += ex;                                                    \
        num += ex * m;                                                \
    }

    int i = start;
    for (; i + 8 <= end; i += 8) {
        int s0 = RFL(src_perm[i + 0]), s1 = RFL(src_perm[i + 1]);
        int s2 = RFL(src_perm[i + 2]), s3 = RFL(src_perm[i + 3]);
        int s4 = RFL(src_perm[i + 4]), s5 = RFL(src_perm[i + 5]);
        int s6 = RFL(src_perm[i + 6]), s7 = RFL(src_perm[i + 7]);
        unsigned short u0 = hl_in[(size_t)s0 * 64 + d];
        unsigned short u1 = hl_in[(size_t)s1 * 64 + d];
        unsigned short u2 = hl_in[(size_t)s2 * 64 + d];
        unsigned short u3 = hl_in[(size_t)s3 * 64 + d];
        unsigned short u4 = hl_in[(size_t)s4 * 64 + d];
        unsigned short u5 = hl_in[(size_t)s5 * 64 + d];
        unsigned short u6 = hl_in[(size_t)s6 * 64 + d];
        unsigned short u7 = hl_in[(size_t)s7 * 64 + d];
        int4 e0 = ea4[i + 0], e1 = ea4[i + 1], e2 = ea4[i + 2], e3 = ea4[i + 3];
        EDGE(u0, e0) EDGE(u1, e1) EDGE(u2, e2) EDGE(u3, e3)
        int4 e4 = ea4[i + 4], e5 = ea4[i + 5], e6 = ea4[i + 6], e7 = ea4[i + 7];
        EDGE(u4, e4) EDGE(u5, e5) EDGE(u6, e6) EDGE(u7, e7)
    }
    for (; i + 4 <= end; i += 4) {
        int s0 = RFL(src_perm[i + 0]), s1 = RFL(src_perm[i + 1]);
        int s2 = RFL(src_perm[i + 2]), s3 = RFL(src_perm[i + 3]);
        unsigned short u0 = hl_in[(size_t)s0 * 64 + d];
        unsigned short u1 = hl_in[(size_t)s1 * 64 + d];
        unsigned short u2 = hl_in[(size_t)s2 * 64 + d];
        unsigned short u3 = hl_in[(size_t)s3 * 64 + d];
        int4 e0 = ea4[i + 0], e1 = ea4[i + 1], e2 = ea4[i + 2], e3 = ea4[i + 3];
        EDGE(u0, e0) EDGE(u1, e1) EDGE(u2, e2) EDGE(u3, e3)
    }
    for (; i < end; ++i) {
        int s0 = RFL(src_perm[i]);
        unsigned short u0 = hl_in[(size_t)s0 * 64 + d];
        int4 e0 = ea4[i];
        EDGE(u0, e0)
    }
#undef EDGE
#undef RFL

    float agg = num / (den + 1e-16f);
    float v = h2f(hl_in[(size_t)n * 64 + d]) + agg;
    v16[(size_t)n * 64 + d] = f2h(v);
}

// ---------------------------------------------------------------------------
// Epilogue: Y += v @ Wm + bm (MFMA), then fused next-LN+ReLU -> hl_out.
template <bool PRODUCE_HL>
__global__ __launch_bounds__(256) void epi_kernel(
    const unsigned short* __restrict__ v16, float* __restrict__ Y,
    const int* __restrict__ wmfrag, const float* __restrict__ bm,
    const float* __restrict__ gnext, const float* __restrict__ bnext,
    unsigned short* __restrict__ hl_out) {
    int tid = threadIdx.x;
    int w = tid >> 6, lane = tid & 63;
    int g = lane >> 4, r = lane & 15;
    int nodebase = blockIdx.x * 64 + w * 16;
    if (nodebase >= N_NODES) return;

    const unsigned short* vp = v16 + (size_t)(nodebase + r) * 64;
    half8 af[2];
#pragma unroll
    for (int m = 0; m < 2; ++m) {
        int k0 = m * 32 + g * 4;
        half4 lo = *(const half4*)(vp + k0);
        half4 hi = *(const half4*)(vp + k0 + 16);
        af[m][0] = lo[0]; af[m][1] = lo[1]; af[m][2] = lo[2]; af[m][3] = lo[3];
        af[m][4] = hi[0]; af[m][5] = hi[1]; af[m][6] = hi[2]; af[m][7] = hi[3];
    }

    const int4* wf4 = (const int4*)wmfrag;
    f32x4 acc[4];
#pragma unroll
    for (int tile = 0; tile < 4; ++tile) {
        float bmv = bm[tile * 16 + r];
        acc[tile] = {bmv, bmv, bmv, bmv};
#pragma unroll
        for (int m = 0; m < 2; ++m) {
            int4 bw = wf4[(tile * 2 + m) * 64 + lane];
            half8 bf = __builtin_bit_cast(half8, bw);
            acc[tile] = __builtin_amdgcn_mfma_f32_16x16x32_f16(af[m], bf, acc[tile], 0, 0, 0);
        }
    }

    float yn[4][4];  // [tile][q]
#pragma unroll
    for (int tile = 0; tile < 4; ++tile) {
#pragma unroll
        for (int q = 0; q < 4; ++q) {
            size_t idx = (size_t)(nodebase + g * 4 + q) * 64 + tile * 16 + r;
            float y = Y[idx] + acc[tile][q];
            yn[tile][q] = y;
            Y[idx] = y;
        }
    }

    if constexpr (PRODUCE_HL) {
        float gnv[4], bnv[4];
#pragma unroll
        for (int tile = 0; tile < 4; ++tile) {
            gnv[tile] = gnext[tile * 16 + r];
            bnv[tile] = bnext[tile * 16 + r];
        }
#pragma unroll
        for (int q = 0; q < 4; ++q) {
            float s = yn[0][q] + yn[1][q] + yn[2][q] + yn[3][q];
            float sq = yn[0][q] * yn[0][q] + yn[1][q] * yn[1][q]
                     + yn[2][q] * yn[2][q] + yn[3][q] * yn[3][q];
            s += __shfl_xor(s, 1, 64);  sq += __shfl_xor(sq, 1, 64);
            s += __shfl_xor(s, 2, 64);  sq += __shfl_xor(sq, 2, 64);
            s += __shfl_xor(s, 4, 64);  sq += __shfl_xor(sq, 4, 64);
            s += __shfl_xor(s, 8, 64);  sq += __shfl_xor(sq, 8, 64);
            float mean = s * (1.f / 64.f);
            float var = sq * (1.f / 64.f) - mean * mean;
            float rs = rsqrtf(var + 1e-5f);
#pragma unroll
            for (int tile = 0; tile < 4; ++tile) {
                float h = (yn[tile][q] - mean) * rs * gnv[tile] + bnv[tile];
                hl_out[(size_t)(nodebase + g * 4 + q) * 64 + tile * 16 + r] =
                    f2h(fmaxf(h, 0.f));
            }
        }
    }
}

// ---------------------------------------------------------------------------
// Final: LN(128) -> relu -> MFMA GEMM @Wp + bp.
__global__ __launch_bounds__(256) void final_kernel(
    const float* __restrict__ A, const float* __restrict__ B,
    const float* __restrict__ lg, const float* __restrict__ lb,
    const int* __restrict__ wpfrag, const float* __restrict__ bp,
    float* __restrict__ out) {
    int tid = threadIdx.x;
    int w = tid >> 6, lane = tid & 63;
    int g = lane >> 4, r = lane & 15;
    int nodebase = blockIdx.x * 64 + w * 16;
    if (nodebase >= N_NODES) return;
    int n = nodebase + r;

    float4 v[8];
    const float4* A4 = (const float4*)(A + (size_t)n * 64);
    const float4* B4 = (const float4*)(B + (size_t)n * 64);
#pragma unroll
    for (int kb = 0; kb < 4; ++kb) v[kb] = A4[kb * 4 + g];
#pragma unroll
    for (int kb = 0; kb < 4; ++kb) v[4 + kb] = B4[kb * 4 + g];

    float s = 0.f, sq = 0.f;
#pragma unroll
    for (int kb = 0; kb < 8; ++kb) {
        s += v[kb].x + v[kb].y + v[kb].z + v[kb].w;
        sq += v[kb].x * v[kb].x + v[kb].y * v[kb].y
            + v[kb].z * v[kb].z + v[kb].w * v[kb].w;
    }
    s += __shfl_xor(s, 16, 64);  sq += __shfl_xor(sq, 16, 64);
    s += __shfl_xor(s, 32, 64);  sq += __shfl_xor(sq, 32, 64);
    float mean = s * (1.f / 128.f);
    float var = sq * (1.f / 128.f) - mean * mean;
    float rs = rsqrtf(var + 1e-5f);

    const float4* lg4 = (const float4*)lg;
    const float4* lb4 = (const float4*)lb;
    half8 afr[4];
#pragma unroll
    for (int kb = 0; kb < 8; ++kb) {
        float4 gv = lg4[kb * 4 + g];
        float4 bv = lb4[kb * 4 + g];
        int m = kb >> 1, e0 = (kb & 1) * 4;
        afr[m][e0 + 0] = (_Float16)fmaxf((v[kb].x - mean) * rs * gv.x + bv.x, 0.f);
        afr[m][e0 + 1] = (_Float16)fmaxf((v[kb].y - mean) * rs * gv.y + bv.y, 0.f);
        afr[m][e0 + 2] = (_Float16)fmaxf((v[kb].z - mean) * rs * gv.z + bv.z, 0.f);
        afr[m][e0 + 3] = (_Float16)fmaxf((v[kb].w - mean) * rs * gv.w + bv.w, 0.f);
    }

    const int4* wf4 = (const int4*)wpfrag;
#pragma unroll
    for (int tile = 0; tile < 7; ++tile) {
        float bias = bp[tile * 16 + r];
        f32x4 acc = {bias, bias, bias, bias};
#pragma unroll
        for (int m = 0; m < 4; ++m) {
            int4 bw = wf4[(tile * 4 + m) * 64 + lane];
            half8 bf = __builtin_bit_cast(half8, bw);
            acc = __builtin_amdgcn_mfma_f32_16x16x32_f16(afr[m], bf, acc, 0, 0, 0);
        }
#pragma unroll
        for (int q = 0; q < 4; ++q) {
            out[(size_t)(nodebase + g * 4 + q) * T_OUT + tile * 16 + r] = acc[q];
        }
    }
}

// ---------------------------------------------------------------------------
extern "C" void kernel_launch(void* const* d_in, const int* in_sizes, int n_in,
                              void* d_out, int out_size, void* d_ws, size_t ws_size,
                              hipStream_t stream) {
    const float* x            = (const float*)d_in[0];
    const int* node_index     = (const int*)d_in[1];
    const int* edge_index     = (const int*)d_in[2];
    const float* edge_attr    = (const float*)d_in[3];
    const float* node_features= (const float*)d_in[4];
    const float* W_oh         = (const float*)d_in[5];
    const float* b_oh         = (const float*)d_in[6];
    const float* W_ne         = (const float*)d_in[7];
    const float* b_ne         = (const float*)d_in[8];
    const float* W_ee         = (const float*)d_in[9];
    const float* b_ee         = (const float*)d_in[10];
    const float* ln_g         = (const float*)d_in[11];
    const float* ln_b         = (const float*)d_in[12];
    const float* We           = (const float*)d_in[13];
    const float* be           = (const float*)d_in[14];
    const float* Wm           = (const float*)d_in[15];
    const float* bm           = (const float*)d_in[16];
    const float* last_g       = (const float*)d_in[17];
    const float* last_b       = (const float*)d_in[18];
    const float* Wp           = (const float*)d_in[19];
    const float* bp           = (const float*)d_in[20];
    float* out = (float*)d_out;

    char* ws = (char*)d_ws;
    size_t off = 0;
    auto alloc = [&](size_t bytes) -> void* {
        void* p = ws + off;
        off = (off + bytes + 255) & ~(size_t)255;
        return p;
    };
    float* A          = (float*)alloc((size_t)N_NODES * 64 * 4);
    float* B          = (float*)alloc((size_t)N_NODES * 64 * 4);
    unsigned short* hl = (unsigned short*)alloc((size_t)N_NODES * 64 * 2);
    unsigned short* v16 = (unsigned short*)alloc((size_t)N_NODES * 64 * 2);
    int* deg          = (int*)alloc((size_t)N_NODES * 4);
    int* rowptr       = (int*)alloc((size_t)(N_NODES + 1) * 4);
    int* rank         = (int*)alloc((size_t)N_EDGES * 4);
    int* src_perm     = (int*)alloc((size_t)N_EDGES * 4);
    int* ea_h         = (int*)alloc((size_t)N_EDGES * 4 * 4);  // half8 per edge
    int* Wc_h2        = (int*)alloc(4 * 256 * 4);
    float* bcomb      = (float*)alloc(4 * 64 * 4);
    int* blocksum     = (int*)alloc((size_t)SCAN_BLOCKS * 4);
    int* blockoff     = (int*)alloc((size_t)SCAN_BLOCKS * 4);
    int* wpfrag       = (int*)alloc((size_t)28 * 64 * 16);     // 28 KB
    int* wmfrag       = (int*)alloc((size_t)32 * 64 * 16);     // 32 KB
    (void)ws_size; (void)in_sizes; (void)n_in; (void)out_size;

    const int NB_NODE = N_NODES / 4;            // 25000
    const int NB_EDGE = (N_EDGES + 255) / 256;  // 6250
    const int NB_EPI  = (N_NODES + 63) / 64;    // 1563

    (void)hipMemsetAsync(deg, 0, (size_t)N_NODES * 4, stream);
    wcomb_kernel<<<4, 64, 0, stream>>>(W_ee, b_ee, We, be, Wc_h2, bcomb);
    wp_pack_kernel<<<28, 64, 0, stream>>>(Wp, wpfrag);
    wm_pack_kernel<<<32, 64, 0, stream>>>(Wm, wmfrag);
    encoder_kernel<<<NB_NODE, 256, 0, stream>>>(x, node_index, node_features,
                                                W_oh, b_oh, W_ne, b_ne, A, B);
    hist_kernel<<<NB_EDGE, 256, 0, stream>>>(edge_index, deg, rank);
    block_sum_kernel<<<SCAN_BLOCKS, 256, 0, stream>>>(deg, blocksum);
    scan_sums_kernel<<<1, 64, 0, stream>>>(blocksum, blockoff, rowptr);
    emit_kernel<<<SCAN_BLOCKS, 256, 0, stream>>>(deg, blockoff, rowptr);
    scatter_kernel<<<NB_EDGE, 256, 0, stream>>>(edge_index, edge_attr, rowptr,
                                                rank, src_perm, ea_h);

    // first gen-block input LN (y_in = B half, params ln[0])
    ln_relu_kernel<<<NB_NODE, 256, 0, stream>>>(B, ln_g, ln_b, hl);

    // gen-block 0: Y = A; produce hl for block 1 (ln[1])
    agg_kernel<<<NB_NODE, 256, 0, stream>>>(hl, v16, rowptr, src_perm, ea_h,
                                            Wc_h2 + 0 * 256, bcomb + 0 * 64);
    epi_kernel<true><<<NB_EPI, 256, 0, stream>>>(
        v16, A, wmfrag + 0 * 8 * 256, bm + 0 * 64,
        ln_g + 1 * 64, ln_b + 1 * 64, hl);
    // gen-block 1: Y = B; produce hl for block 2 (ln[2])
    agg_kernel<<<NB_NODE, 256, 0, stream>>>(hl, v16, rowptr, src_perm, ea_h,
                                            Wc_h2 + 1 * 256, bcomb + 1 * 64);
    epi_kernel<true><<<NB_EPI, 256, 0, stream>>>(
        v16, B, wmfrag + 1 * 8 * 256, bm + 1 * 64,
        ln_g + 2 * 64, ln_b + 2 * 64, hl);
    // gen-block 2: Y = A; produce hl for block 3 (ln[3])
    agg_kernel<<<NB_NODE, 256, 0, stream>>>(hl, v16, rowptr, src_perm, ea_h,
                                            Wc_h2 + 2 * 256, bcomb + 2 * 64);
    epi_kernel<true><<<NB_EPI, 256, 0, stream>>>(
        v16, A, wmfrag + 2 * 8 * 256, bm + 2 * 64,
        ln_g + 3 * 64, ln_b + 3 * 64, hl);
    // gen-block 3: Y = B; no hl production
    agg_kernel<<<NB_NODE, 256, 0, stream>>>(hl, v16, rowptr, src_perm, ea_h,
                                            Wc_h2 + 3 * 256, bcomb + 3 * 64);
    epi_kernel<false><<<NB_EPI, 256, 0, stream>>>(
        v16, B, wmfrag + 3 * 8 * 256, bm + 3 * 64,
        nullptr, nullptr, nullptr);

    final_kernel<<<NB_EPI, 256, 0, stream>>>(A, B, last_g, last_b, wpfrag, bp, out);
}

// Round 10
// 607.954 us; speedup vs baseline: 1.4742x; 1.0059x over previous
//
#include <hip/hip_runtime.h>

constexpr int N_NODES = 100000;
constexpr int N_EDGES = 1600000;
constexpr int T_OUT = 112;

constexpr int SCAN_CHUNK = 1024;
constexpr int SCAN_BLOCKS = (N_NODES + SCAN_CHUNK - 1) / SCAN_CHUNK;  // 98

typedef _Float16 h2v __attribute__((ext_vector_type(2)));
typedef _Float16 half4 __attribute__((ext_vector_type(4)));
typedef _Float16 half8 __attribute__((ext_vector_type(8)));
typedef float f32x4 __attribute__((ext_vector_type(4)));
typedef int i4v __attribute__((ext_vector_type(4)));
typedef float f4v __attribute__((ext_vector_type(4)));

__device__ __forceinline__ float dot2h(h2v a, h2v b, float c) {
#if __has_builtin(__builtin_amdgcn_fdot2)
    return __builtin_amdgcn_fdot2(a, b, c, false);
#else
    return fmaf((float)a.x, (float)b.x, fmaf((float)a.y, (float)b.y, c));
#endif
}
__device__ __forceinline__ int pk2(float a, float b) {
    auto v = __builtin_amdgcn_cvt_pkrtz(a, b);
    return __builtin_bit_cast(int, v);
}
__device__ __forceinline__ h2v b2h(int x) { return __builtin_bit_cast(h2v, x); }
__device__ __forceinline__ unsigned short f2h(float f) {
    return __builtin_bit_cast(unsigned short, (_Float16)f);
}
__device__ __forceinline__ float h2f(unsigned short u) {
    return (float)__builtin_bit_cast(_Float16, u);
}

// ---------------------------------------------------------------------------
// Wc_h2[lg][4][64] (half2-packed input-channel pairs), bcomb[lg][64].
__global__ void wcomb_kernel(const float* __restrict__ W_ee,
                             const float* __restrict__ b_ee,
                             const float* __restrict__ We,
                             const float* __restrict__ be,
                             int* __restrict__ Wc_h2,
                             float* __restrict__ bcomb) {
    int lg = blockIdx.x;
    int d = threadIdx.x;
    const float* We_ = We + (size_t)lg * 128 * 64;
    float acc[9];
#pragma unroll
    for (int k = 0; k < 9; ++k) acc[k] = 0.f;
    for (int c = 0; c < 128; ++c) {
        float wv = We_[c * 64 + d];
#pragma unroll
        for (int k = 0; k < 8; ++k) acc[k] += W_ee[k * 128 + c] * wv;
        acc[8] += b_ee[c] * wv;
    }
#pragma unroll
    for (int j = 0; j < 4; ++j)
        Wc_h2[lg * 256 + j * 64 + d] = pk2(acc[2 * j], acc[2 * j + 1]);
    bcomb[lg * 64 + d] = acc[8] + be[lg * 64 + d];
}

// ---------------------------------------------------------------------------
// Pack Wp[128][112] fp32 -> fp16 MFMA B-fragments (7 tiles x 4 K-halves).
__global__ void wp_pack_kernel(const float* __restrict__ Wp, int* __restrict__ wpfrag) {
    int tm = blockIdx.x;  // 0..27
    int tile = tm >> 2, m = tm & 3;
    int lane = threadIdx.x;
    int g = lane >> 4, r = lane & 15;
    int t = tile * 16 + r;
    int o[4];
#pragma unroll
    for (int p = 0; p < 4; ++p) {
        int j0 = 2 * p, j1 = 2 * p + 1;
        int k0 = m * 32 + (j0 >> 2) * 16 + g * 4 + (j0 & 3);
        int k1 = m * 32 + (j1 >> 2) * 16 + g * 4 + (j1 & 3);
        o[p] = pk2(Wp[k0 * 112 + t], Wp[k1 * 112 + t]);
    }
    int4 o4; o4.x = o[0]; o4.y = o[1]; o4.z = o[2]; o4.w = o[3];
    *(int4*)(wpfrag + ((size_t)tm * 64 + lane) * 4) = o4;
}

// Pack Wm[lg][64][64] fp32 -> fp16 MFMA B-fragments (4 tiles x 2 K-halves per lg).
__global__ void wm_pack_kernel(const float* __restrict__ Wm, int* __restrict__ wmfrag) {
    int b = blockIdx.x;  // lg*8 + tile*2 + m, 32 blocks
    int lg = b >> 3, tm = b & 7;
    int tile = tm >> 1, m = tm & 1;
    int lane = threadIdx.x;
    int g = lane >> 4, r = lane & 15;
    const float* W = Wm + (size_t)lg * 4096;
    int col = tile * 16 + r;
    int o[4];
#pragma unroll
    for (int p = 0; p < 4; ++p) {
        int j0 = 2 * p, j1 = 2 * p + 1;
        int k0 = m * 32 + (j0 >> 2) * 16 + g * 4 + (j0 & 3);
        int k1 = m * 32 + (j1 >> 2) * 16 + g * 4 + (j1 & 3);
        o[p] = pk2(W[k0 * 64 + col], W[k1 * 64 + col]);
    }
    int4 o4; o4.x = o[0]; o4.y = o[1]; o4.z = o[2]; o4.w = o[3];
    *(int4*)(wmfrag + ((size_t)b * 64 + lane) * 4) = o4;
}

// ---------------------------------------------------------------------------
__global__ __launch_bounds__(256) void encoder_kernel(
    const float* __restrict__ x, const int* __restrict__ node_index,
    const float* __restrict__ node_features,
    const float* __restrict__ W_oh, const float* __restrict__ b_oh,
    const float* __restrict__ W_ne, const float* __restrict__ b_ne,
    float* __restrict__ A, float* __restrict__ B) {
    int tid = threadIdx.x;
    int w = tid >> 6, d = tid & 63;
    int n = blockIdx.x * 4 + w;

    float xf[8];
    const float* xr = x + (size_t)n * 8;
#pragma unroll
    for (int j = 0; j < 8; ++j) xf[j] = xr[j];

    float nf[16];
    int ni = node_index[n];
    const float* nfr = node_features + (size_t)ni * 8;
#pragma unroll
    for (int k = 0; k < 8; ++k) nf[k] = nfr[k];
#pragma unroll
    for (int k = 0; k < 8; ++k) {
        float acc = b_oh[k];
#pragma unroll
        for (int j = 0; j < 8; ++j) acc += xf[j] * W_oh[j * 8 + k];
        nf[8 + k] = acc;
    }
    float hA = b_ne[d], hB = b_ne[64 + d];
#pragma unroll
    for (int k = 0; k < 16; ++k) {
        hA += nf[k] * W_ne[k * 128 + d];
        hB += nf[k] * W_ne[k * 128 + 64 + d];
    }
    A[(size_t)n * 64 + d] = hA;
    B[(size_t)n * 64 + d] = hB;
}

// ---------------------------------------------------------------------------
// CSR build. hist also records each edge's within-node rank (atomic return),
// making the scatter pass atomic-free: slot = rowptr[dst] + rank.
__global__ void hist_kernel(const int* __restrict__ edge_index,
                            int* __restrict__ deg, int* __restrict__ rank) {
    int e = blockIdx.x * 256 + threadIdx.x;
    if (e < N_EDGES) rank[e] = atomicAdd(&deg[edge_index[N_EDGES + e]], 1);
}

__global__ __launch_bounds__(256) void block_sum_kernel(const int* __restrict__ deg,
                                                        int* __restrict__ blocksum) {
    __shared__ int s_w[4];
    int t = threadIdx.x;
    int base = blockIdx.x * SCAN_CHUNK + t * 4;
    int s = 0;
    if (base + 3 < N_NODES) {
        int4 v = *(const int4*)(deg + base);
        s = v.x + v.y + v.z + v.w;
    } else {
        for (int j = 0; j < 4; ++j)
            if (base + j < N_NODES) s += deg[base + j];
    }
#pragma unroll
    for (int o = 32; o >= 1; o >>= 1) s += __shfl_xor(s, o, 64);
    if ((t & 63) == 0) s_w[t >> 6] = s;
    __syncthreads();
    if (t == 0) blocksum[blockIdx.x] = s_w[0] + s_w[1] + s_w[2] + s_w[3];
}

__global__ __launch_bounds__(64) void scan_sums_kernel(const int* __restrict__ blocksum,
                                                       int* __restrict__ blockoff,
                                                       int* __restrict__ rowptr) {
    int t = threadIdx.x;
    int i0 = 2 * t, i1 = 2 * t + 1;
    int v0 = (i0 < SCAN_BLOCKS) ? blocksum[i0] : 0;
    int v1 = (i1 < SCAN_BLOCKS) ? blocksum[i1] : 0;
    int s = v0 + v1;
    int incl = s;
#pragma unroll
    for (int o = 1; o < 64; o <<= 1) {
        int u = __shfl_up(incl, o, 64);
        if (t >= o) incl += u;
    }
    int excl = incl - s;
    if (i0 < SCAN_BLOCKS) blockoff[i0] = excl;
    if (i1 < SCAN_BLOCKS) blockoff[i1] = excl + v0;
    if (t == 63) rowptr[N_NODES] = incl;
}

__global__ __launch_bounds__(256) void emit_kernel(const int* __restrict__ deg,
                                                   const int* __restrict__ blockoff,
                                                   int* __restrict__ rowptr) {
    __shared__ int s_w[4];
    int t = threadIdx.x;
    int w = t >> 6, lane = t & 63;
    int base = blockIdx.x * SCAN_CHUNK + t * 4;

    int d0 = 0, d1 = 0, d2 = 0, d3 = 0;
    if (base + 3 < N_NODES) {
        int4 v = *(const int4*)(deg + base);
        d0 = v.x; d1 = v.y; d2 = v.z; d3 = v.w;
    } else {
        if (base + 0 < N_NODES) d0 = deg[base + 0];
        if (base + 1 < N_NODES) d1 = deg[base + 1];
        if (base + 2 < N_NODES) d2 = deg[base + 2];
        if (base + 3 < N_NODES) d3 = deg[base + 3];
    }
    int s = d0 + d1 + d2 + d3;
    int incl = s;
#pragma unroll
    for (int o = 1; o < 64; o <<= 1) {
        int u = __shfl_up(incl, o, 64);
        if (lane >= o) incl += u;
    }
    if (lane == 63) s_w[w] = incl;
    __syncthreads();
    int woff = 0;
    for (int j = 0; j < 4; ++j) woff += (j < w) ? s_w[j] : 0;

    int p = blockoff[blockIdx.x] + woff + incl - s;
    int4 r;
    r.x = p;
    r.y = p + d0;
    r.z = p + d0 + d1;
    r.w = p + d0 + d1 + d2;
    if (base + 3 < N_NODES) {
        *(int4*)(rowptr + base) = r;
    } else {
        if (base + 0 < N_NODES) rowptr[base + 0] = r.x;
        if (base + 1 < N_NODES) rowptr[base + 1] = r.y;
        if (base + 2 < N_NODES) rowptr[base + 2] = r.z;
        if (base + 3 < N_NODES) rowptr[base + 3] = r.w;
    }
}

// Atomic-free scatter: slot = rowptr[dst] + rank (precomputed in hist).
__global__ void scatter_kernel(const int* __restrict__ edge_index,
                               const float* __restrict__ edge_attr,
                               const int* __restrict__ rowptr,
                               const int* __restrict__ rank,
                               int* __restrict__ src_perm,
                               int* __restrict__ ea_h) {
    int e = blockIdx.x * 256 + threadIdx.x;
    if (e >= N_EDGES) return;
    int dn = edge_index[N_EDGES + e];
    int idx = rowptr[dn] + rank[e];
    f4v a = __builtin_nontemporal_load((const f4v*)(edge_attr + (size_t)e * 8));
    f4v b = __builtin_nontemporal_load((const f4v*)(edge_attr + (size_t)e * 8 + 4));
    i4v o;
    o.x = pk2(a.x, a.y);
    o.y = pk2(a.z, a.w);
    o.z = pk2(b.x, b.y);
    o.w = pk2(b.z, b.w);
    __builtin_nontemporal_store(o, (i4v*)(ea_h + (size_t)idx * 4));
    __builtin_nontemporal_store(edge_index[e], src_perm + idx);
}

// ---------------------------------------------------------------------------
// hl (fp16) = relu(LayerNorm(Y) * g + b) — first gen-block input only.
__global__ __launch_bounds__(256) void ln_relu_kernel(const float* __restrict__ Y,
                                                      const float* __restrict__ g,
                                                      const float* __restrict__ b,
                                                      unsigned short* __restrict__ hl16) {
    int tid = threadIdx.x;
    int w = tid >> 6, d = tid & 63;
    int n = blockIdx.x * 4 + w;
    float y = Y[(size_t)n * 64 + d];
    float s = y, sq = y * y;
#pragma unroll
    for (int offd = 32; offd >= 1; offd >>= 1) {
        s += __shfl_xor(s, offd, 64);
        sq += __shfl_xor(sq, offd, 64);
    }
    float mean = s * (1.f / 64.f);
    float var = sq * (1.f / 64.f) - mean * mean;
    float rs = rsqrtf(var + 1e-5f);
    float h = (y - mean) * rs * g[d] + b[d];
    hl16[(size_t)n * 64 + d] = f2h(fmaxf(h, 0.f));
}

// ---------------------------------------------------------------------------
// Gather + scatter-softmax aggregation. TWO nodes per wave: each 32-lane
// half-wave owns one node; each lane owns a channel PAIR (ushort2 = 4 B).
// Per-edge hl gather = one 64 B line (was two). No LDS, no barriers.
__global__ __launch_bounds__(256) void agg_kernel(
    const unsigned short* __restrict__ hl_in, unsigned short* __restrict__ v16,
    const int* __restrict__ rowptr, const int* __restrict__ src_perm,
    const int* __restrict__ ea_h,
    const int* __restrict__ Wc_h2, const float* __restrict__ bcomb) {
    int tid = threadIdx.x;
    int w = tid >> 6, lane = tid & 63;
    int half = lane >> 5;
    int c = (lane & 31) * 2;                    // channel pair base
    int n = blockIdx.x * 8 + w * 2 + half;      // 8 nodes per 256-thr block

    // weights for channels c and c+1: 4 h2v each (input-channel pairs)
    h2v wc0[4], wc1[4];
#pragma unroll
    for (int j = 0; j < 4; ++j) {
        wc0[j] = b2h(Wc_h2[j * 64 + c]);
        wc1[j] = b2h(Wc_h2[j * 64 + c + 1]);
    }
    float bc0 = bcomb[c], bc1 = bcomb[c + 1];

    float num0 = 0.f, den0 = 0.f, num1 = 0.f, den1 = 0.f;
    int start = rowptr[n], end = rowptr[n + 1];
    const int4* ea4 = (const int4*)ea_h;

#define EDGE(U, E)                                                        \
    {                                                                     \
        h2v hv = b2h((int)(U));                                           \
        float eW0 = bc0, eW1 = bc1;                                       \
        eW0 = dot2h(b2h(E.x), wc0[0], eW0);                               \
        eW1 = dot2h(b2h(E.x), wc1[0], eW1);                               \
        eW0 = dot2h(b2h(E.y), wc0[1], eW0);                               \
        eW1 = dot2h(b2h(E.y), wc1[1], eW1);                               \
        eW0 = dot2h(b2h(E.z), wc0[2], eW0);                               \
        eW1 = dot2h(b2h(E.z), wc1[2], eW1);                               \
        eW0 = dot2h(b2h(E.w), wc0[3], eW0);                               \
        eW1 = dot2h(b2h(E.w), wc1[3], eW1);                               \
        float m0 = fmaxf((float)hv.x + eW0, 0.f) + 1e-7f;                 \
        float m1 = fmaxf((float)hv.y + eW1, 0.f) + 1e-7f;                 \
        float x0 = __expf(m0), x1 = __expf(m1);                           \
        den0 += x0; num0 += x0 * m0;                                      \
        den1 += x1; num1 += x1 * m1;                                      \
    }

    int i = start;
    for (; i + 4 <= end; i += 4) {
        int s0 = src_perm[i + 0];
        int s1 = src_perm[i + 1];
        int s2 = src_perm[i + 2];
        int s3 = src_perm[i + 3];
        unsigned int u0 = *(const unsigned int*)(hl_in + (size_t)s0 * 64 + c);
        unsigned int u1 = *(const unsigned int*)(hl_in + (size_t)s1 * 64 + c);
        unsigned int u2 = *(const unsigned int*)(hl_in + (size_t)s2 * 64 + c);
        unsigned int u3 = *(const unsigned int*)(hl_in + (size_t)s3 * 64 + c);
        int4 e0 = ea4[i + 0], e1 = ea4[i + 1], e2 = ea4[i + 2], e3 = ea4[i + 3];
        EDGE(u0, e0) EDGE(u1, e1) EDGE(u2, e2) EDGE(u3, e3)
    }
    for (; i < end; ++i) {
        int s0 = src_perm[i];
        unsigned int u0 = *(const unsigned int*)(hl_in + (size_t)s0 * 64 + c);
        int4 e0 = ea4[i];
        EDGE(u0, e0)
    }
#undef EDGE

    float agg0 = num0 / (den0 + 1e-16f);
    float agg1 = num1 / (den1 + 1e-16f);
    unsigned int uself = *(const unsigned int*)(hl_in + (size_t)n * 64 + c);
    h2v sv = b2h((int)uself);
    int vout = pk2((float)sv.x + agg0, (float)sv.y + agg1);
    *(int*)(v16 + (size_t)n * 64 + c) = vout;
}

// ---------------------------------------------------------------------------
// Epilogue: Y += v @ Wm + bm (MFMA), then fused next-LN+ReLU -> hl_out.
template <bool PRODUCE_HL>
__global__ __launch_bounds__(256) void epi_kernel(
    const unsigned short* __restrict__ v16, float* __restrict__ Y,
    const int* __restrict__ wmfrag, const float* __restrict__ bm,
    const float* __restrict__ gnext, const float* __restrict__ bnext,
    unsigned short* __restrict__ hl_out) {
    int tid = threadIdx.x;
    int w = tid >> 6, lane = tid & 63;
    int g = lane >> 4, r = lane & 15;
    int nodebase = blockIdx.x * 64 + w * 16;
    if (nodebase >= N_NODES) return;

    const unsigned short* vp = v16 + (size_t)(nodebase + r) * 64;
    half8 af[2];
#pragma unroll
    for (int m = 0; m < 2; ++m) {
        int k0 = m * 32 + g * 4;
        half4 lo = *(const half4*)(vp + k0);
        half4 hi = *(const half4*)(vp + k0 + 16);
        af[m][0] = lo[0]; af[m][1] = lo[1]; af[m][2] = lo[2]; af[m][3] = lo[3];
        af[m][4] = hi[0]; af[m][5] = hi[1]; af[m][6] = hi[2]; af[m][7] = hi[3];
    }

    const int4* wf4 = (const int4*)wmfrag;
    f32x4 acc[4];
#pragma unroll
    for (int tile = 0; tile < 4; ++tile) {
        float bmv = bm[tile * 16 + r];
        acc[tile] = {bmv, bmv, bmv, bmv};
#pragma unroll
        for (int m = 0; m < 2; ++m) {
            int4 bw = wf4[(tile * 2 + m) * 64 + lane];
            half8 bf = __builtin_bit_cast(half8, bw);
            acc[tile] = __builtin_amdgcn_mfma_f32_16x16x32_f16(af[m], bf, acc[tile], 0, 0, 0);
        }
    }

    float yn[4][4];  // [tile][q]
#pragma unroll
    for (int tile = 0; tile < 4; ++tile) {
#pragma unroll
        for (int q = 0; q < 4; ++q) {
            size_t idx = (size_t)(nodebase + g * 4 + q) * 64 + tile * 16 + r;
            float y = Y[idx] + acc[tile][q];
            yn[tile][q] = y;
            Y[idx] = y;
        }
    }

    if constexpr (PRODUCE_HL) {
        float gnv[4], bnv[4];
#pragma unroll
        for (int tile = 0; tile < 4; ++tile) {
            gnv[tile] = gnext[tile * 16 + r];
            bnv[tile] = bnext[tile * 16 + r];
        }
#pragma unroll
        for (int q = 0; q < 4; ++q) {
            float s = yn[0][q] + yn[1][q] + yn[2][q] + yn[3][q];
            float sq = yn[0][q] * yn[0][q] + yn[1][q] * yn[1][q]
                     + yn[2][q] * yn[2][q] + yn[3][q] * yn[3][q];
            s += __shfl_xor(s, 1, 64);  sq += __shfl_xor(sq, 1, 64);
            s += __shfl_xor(s, 2, 64);  sq += __shfl_xor(sq, 2, 64);
            s += __shfl_xor(s, 4, 64);  sq += __shfl_xor(sq, 4, 64);
            s += __shfl_xor(s, 8, 64);  sq += __shfl_xor(sq, 8, 64);
            float mean = s * (1.f / 64.f);
            float var = sq * (1.f / 64.f) - mean * mean;
            float rs = rsqrtf(var + 1e-5f);
#pragma unroll
            for (int tile = 0; tile < 4; ++tile) {
                float h = (yn[tile][q] - mean) * rs * gnv[tile] + bnv[tile];
                hl_out[(size_t)(nodebase + g * 4 + q) * 64 + tile * 16 + r] =
                    f2h(fmaxf(h, 0.f));
            }
        }
    }
}

// ---------------------------------------------------------------------------
// Final: LN(128) -> relu -> MFMA GEMM @Wp + bp.
__global__ __launch_bounds__(256) void final_kernel(
    const float* __restrict__ A, const float* __restrict__ B,
    const float* __restrict__ lg, const float* __restrict__ lb,
    const int* __restrict__ wpfrag, const float* __restrict__ bp,
    float* __restrict__ out) {
    int tid = threadIdx.x;
    int w = tid >> 6, lane = tid & 63;
    int g = lane >> 4, r = lane & 15;
    int nodebase = blockIdx.x * 64 + w * 16;
    if (nodebase >= N_NODES) return;
    int n = nodebase + r;

    float4 v[8];
    const float4* A4 = (const float4*)(A + (size_t)n * 64);
    const float4* B4 = (const float4*)(B + (size_t)n * 64);
#pragma unroll
    for (int kb = 0; kb < 4; ++kb) v[kb] = A4[kb * 4 + g];
#pragma unroll
    for (int kb = 0; kb < 4; ++kb) v[4 + kb] = B4[kb * 4 + g];

    float s = 0.f, sq = 0.f;
#pragma unroll
    for (int kb = 0; kb < 8; ++kb) {
        s += v[kb].x + v[kb].y + v[kb].z + v[kb].w;
        sq += v[kb].x * v[kb].x + v[kb].y * v[kb].y
            + v[kb].z * v[kb].z + v[kb].w * v[kb].w;
    }
    s += __shfl_xor(s, 16, 64);  sq += __shfl_xor(sq, 16, 64);
    s += __shfl_xor(s, 32, 64);  sq += __shfl_xor(sq, 32, 64);
    float mean = s * (1.f / 128.f);
    float var = sq * (1.f / 128.f) - mean * mean;
    float rs = rsqrtf(var + 1e-5f);

    const float4* lg4 = (const float4*)lg;
    const float4* lb4 = (const float4*)lb;
    half8 afr[4];
#pragma unroll
    for (int kb = 0; kb < 8; ++kb) {
        float4 gv = lg4[kb * 4 + g];
        float4 bv = lb4[kb * 4 + g];
        int m = kb >> 1, e0 = (kb & 1) * 4;
        afr[m][e0 + 0] = (_Float16)fmaxf((v[kb].x - mean) * rs * gv.x + bv.x, 0.f);
        afr[m][e0 + 1] = (_Float16)fmaxf((v[kb].y - mean) * rs * gv.y + bv.y, 0.f);
        afr[m][e0 + 2] = (_Float16)fmaxf((v[kb].z - mean) * rs * gv.z + bv.z, 0.f);
        afr[m][e0 + 3] = (_Float16)fmaxf((v[kb].w - mean) * rs * gv.w + bv.w, 0.f);
    }

    const int4* wf4 = (const int4*)wpfrag;
#pragma unroll
    for (int tile = 0; tile < 7; ++tile) {
        float bias = bp[tile * 16 + r];
        f32x4 acc = {bias, bias, bias, bias};
#pragma unroll
        for (int m = 0; m < 4; ++m) {
            int4 bw = wf4[(tile * 4 + m) * 64 + lane];
            half8 bf = __builtin_bit_cast(half8, bw);
            acc = __builtin_amdgcn_mfma_f32_16x16x32_f16(afr[m], bf, acc, 0, 0, 0);
        }
#pragma unroll
        for (int q = 0; q < 4; ++q) {
            out[(size_t)(nodebase + g * 4 + q) * T_OUT + tile * 16 + r] = acc[q];
        }
    }
}

// ---------------------------------------------------------------------------
extern "C" void kernel_launch(void* const* d_in, const int* in_sizes, int n_in,
                              void* d_out, int out_size, void* d_ws, size_t ws_size,
                              hipStream_t stream) {
    const float* x            = (const float*)d_in[0];
    const int* node_index     = (const int*)d_in[1];
    const int* edge_index     = (const int*)d_in[2];
    const float* edge_attr    = (const float*)d_in[3];
    const float* node_features= (const float*)d_in[4];
    const float* W_oh         = (const float*)d_in[5];
    const float* b_oh         = (const float*)d_in[6];
    const float* W_ne         = (const float*)d_in[7];
    const float* b_ne         = (const float*)d_in[8];
    const float* W_ee         = (const float*)d_in[9];
    const float* b_ee         = (const float*)d_in[10];
    const float* ln_g         = (const float*)d_in[11];
    const float* ln_b         = (const float*)d_in[12];
    const float* We           = (const float*)d_in[13];
    const float* be           = (const float*)d_in[14];
    const float* Wm           = (const float*)d_in[15];
    const float* bm           = (const float*)d_in[16];
    const float* last_g       = (const float*)d_in[17];
    const float* last_b       = (const float*)d_in[18];
    const float* Wp           = (const float*)d_in[19];
    const float* bp           = (const float*)d_in[20];
    float* out = (float*)d_out;

    char* ws = (char*)d_ws;
    size_t off = 0;
    auto alloc = [&](size_t bytes) -> void* {
        void* p = ws + off;
        off = (off + bytes + 255) & ~(size_t)255;
        return p;
    };
    float* A          = (float*)alloc((size_t)N_NODES * 64 * 4);
    float* B          = (float*)alloc((size_t)N_NODES * 64 * 4);
    unsigned short* hl = (unsigned short*)alloc((size_t)N_NODES * 64 * 2);
    unsigned short* v16 = (unsigned short*)alloc((size_t)N_NODES * 64 * 2);
    int* deg          = (int*)alloc((size_t)N_NODES * 4);
    int* rowptr       = (int*)alloc((size_t)(N_NODES + 1) * 4);
    int* rank         = (int*)alloc((size_t)N_EDGES * 4);
    int* src_perm     = (int*)alloc((size_t)N_EDGES * 4);
    int* ea_h         = (int*)alloc((size_t)N_EDGES * 4 * 4);  // half8 per edge
    int* Wc_h2        = (int*)alloc(4 * 256 * 4);
    float* bcomb      = (float*)alloc(4 * 64 * 4);
    int* blocksum     = (int*)alloc((size_t)SCAN_BLOCKS * 4);
    int* blockoff     = (int*)alloc((size_t)SCAN_BLOCKS * 4);
    int* wpfrag       = (int*)alloc((size_t)28 * 64 * 16);     // 28 KB
    int* wmfrag       = (int*)alloc((size_t)32 * 64 * 16);     // 32 KB
    (void)ws_size; (void)in_sizes; (void)n_in; (void)out_size;

    const int NB_NODE = N_NODES / 4;            // 25000
    const int NB_EDGE = (N_EDGES + 255) / 256;  // 6250
    const int NB_AGG  = N_NODES / 8;            // 12500 (8 nodes/block)
    const int NB_EPI  = (N_NODES + 63) / 64;    // 1563

    (void)hipMemsetAsync(deg, 0, (size_t)N_NODES * 4, stream);
    wcomb_kernel<<<4, 64, 0, stream>>>(W_ee, b_ee, We, be, Wc_h2, bcomb);
    wp_pack_kernel<<<28, 64, 0, stream>>>(Wp, wpfrag);
    wm_pack_kernel<<<32, 64, 0, stream>>>(Wm, wmfrag);
    encoder_kernel<<<NB_NODE, 256, 0, stream>>>(x, node_index, node_features,
                                                W_oh, b_oh, W_ne, b_ne, A, B);
    hist_kernel<<<NB_EDGE, 256, 0, stream>>>(edge_index, deg, rank);
    block_sum_kernel<<<SCAN_BLOCKS, 256, 0, stream>>>(deg, blocksum);
    scan_sums_kernel<<<1, 64, 0, stream>>>(blocksum, blockoff, rowptr);
    emit_kernel<<<SCAN_BLOCKS, 256, 0, stream>>>(deg, blockoff, rowptr);
    scatter_kernel<<<NB_EDGE, 256, 0, stream>>>(edge_index, edge_attr, rowptr,
                                                rank, src_perm, ea_h);

    // first gen-block input LN (y_in = B half, params ln[0])
    ln_relu_kernel<<<NB_NODE, 256, 0, stream>>>(B, ln_g, ln_b, hl);

    // gen-block 0: Y = A; produce hl for block 1 (ln[1])
    agg_kernel<<<NB_AGG, 256, 0, stream>>>(hl, v16, rowptr, src_perm, ea_h,
                                           Wc_h2 + 0 * 256, bcomb + 0 * 64);
    epi_kernel<true><<<NB_EPI, 256, 0, stream>>>(
        v16, A, wmfrag + 0 * 8 * 256, bm + 0 * 64,
        ln_g + 1 * 64, ln_b + 1 * 64, hl);
    // gen-block 1: Y = B; produce hl for block 2 (ln[2])
    agg_kernel<<<NB_AGG, 256, 0, stream>>>(hl, v16, rowptr, src_perm, ea_h,
                                           Wc_h2 + 1 * 256, bcomb + 1 * 64);
    epi_kernel<true><<<NB_EPI, 256, 0, stream>>>(
        v16, B, wmfrag + 1 * 8 * 256, bm + 1 * 64,
        ln_g + 2 * 64, ln_b + 2 * 64, hl);
    // gen-block 2: Y = A; produce hl for block 3 (ln[3])
    agg_kernel<<<NB_AGG, 256, 0, stream>>>(hl, v16, rowptr, src_perm, ea_h,
                                           Wc_h2 + 2 * 256, bcomb + 2 * 64);
    epi_kernel<true><<<NB_EPI, 256, 0, stream>>>(
        v16, A, wmfrag + 2 * 8 * 256, bm + 2 * 64,
        ln_g + 3 * 64, ln_b + 3 * 64, hl);
    // gen-block 3: Y = B; no hl production
    agg_kernel<<<NB_AGG, 256, 0, stream>>>(hl, v16, rowptr, src_perm, ea_h,
                                           Wc_h2 + 3 * 256, bcomb + 3 * 64);
    epi_kernel<false><<<NB_EPI, 256, 0, stream>>>(
        v16, B, wmfrag + 3 * 8 * 256, bm + 3 * 64,
        nullptr, nullptr, nullptr);

    final_kernel<<<NB_EPI, 256, 0, stream>>>(A, B, last_g, last_b, wpfrag, bp, out);
}